// Round 3
// baseline (4303.812 us; speedup 1.0000x reference)
//
#include <hip/hip_runtime.h>

typedef unsigned short u16;

static constexpr int Bn  = 4;
static constexpr int C   = 512;
static constexpr int HW  = 4096;
static constexpr int HID = 256;

__device__ __forceinline__ u16 f2bf(float f){
  union { float f; unsigned int i; } x; x.f = f;
  return (u16)((x.i + 0x7fffu + ((x.i >> 16) & 1u)) >> 16);
}
// load 4 consecutive bf16 (8B aligned) -> float4, exact
__device__ __forceinline__ float4 bf4(const u16* p){
  uint2 u = *(const uint2*)p;
  union { unsigned int i; float f; } a,b,c,d;
  a.i = u.x << 16; b.i = u.x & 0xffff0000u;
  c.i = u.y << 16; d.i = u.y & 0xffff0000u;
  return make_float4(a.f, b.f, c.f, d.f);
}

// shared 64x64 tile micro-kernel: 4x4 accum per thread, 16-deep K slab
__device__ __forceinline__ void mm16(const float (*As)[64], const float (*Bs)[64],
                                     float acc[4][4], int ty, int tx){
  #pragma unroll
  for (int kk = 0; kk < 16; ++kk){
    float a[4], b[4];
    #pragma unroll
    for (int i = 0; i < 4; ++i) a[i] = As[kk][ty*4+i];
    #pragma unroll
    for (int j = 0; j < 4; ++j) b[j] = Bs[kk][tx*4+j];
    #pragma unroll
    for (int i = 0; i < 4; ++i)
      #pragma unroll
      for (int j = 0; j < 4; ++j)
        acc[i][j] += a[i]*b[j];
  }
}

// per (tensor, b, c): mean + rstd over 4096 spatial (unbiased var, eps 1e-5)
__global__ __launch_bounds__(256) void k_stats(const float* __restrict__ content,
                                               const float* __restrict__ style,
                                               float2* __restrict__ statsC,
                                               float2* __restrict__ statsS){
  const int bc = blockIdx.x;
  const float* X = (blockIdx.y == 0 ? content : style) + (size_t)bc * HW;
  float s = 0.f, sq = 0.f;
  for (int i = threadIdx.x; i < HW; i += 256){
    float v = X[i]; s += v; sq += v*v;
  }
  __shared__ float rs[256], rq[256];
  rs[threadIdx.x] = s; rq[threadIdx.x] = sq; __syncthreads();
  for (int o = 128; o > 0; o >>= 1){
    if (threadIdx.x < o){ rs[threadIdx.x] += rs[threadIdx.x+o]; rq[threadIdx.x] += rq[threadIdx.x+o]; }
    __syncthreads();
  }
  if (threadIdx.x == 0){
    float mean = rs[0] / (float)HW;
    float var  = (rq[0] - rs[0]*mean) / (float)(HW - 1);
    float rstd = rsqrtf(var + 1e-5f);
    (blockIdx.y == 0 ? statsC : statsS)[bc] = make_float2(mean, rstd);
  }
}

// per (tensor, b, k): 1 / max(||x[b,:,k]||2, 1e-12)
__global__ __launch_bounds__(256) void k_pixnorm(const float* __restrict__ content,
                                                 const float* __restrict__ style,
                                                 float* __restrict__ inc,
                                                 float* __restrict__ ins){
  const int b = blockIdx.y;
  const int k = blockIdx.x * 256 + threadIdx.x;
  const float* X = (blockIdx.z == 0 ? content : style) + (size_t)b * C * HW + k;
  float acc = 0.f;
  for (int c = 0; c < C; ++c){ float v = X[(size_t)c * HW]; acc += v*v; }
  float inv = 1.f / fmaxf(sqrtf(acc), 1e-12f);
  (blockIdx.z == 0 ? inc : ins)[b*HW + k] = inv;
}

// out[o,k] = bias[o] + sum_c W[o,c] * mvn?(X[c,k]) ; out fp32 [512][4096]
__global__ __launch_bounds__(256) void k_conv(const float* __restrict__ W,
                                              const float* __restrict__ X,
                                              const float* __restrict__ bias,
                                              const float2* __restrict__ stats,
                                              int use_mvn,
                                              float* __restrict__ out){
  __shared__ float As[16][64];   // [c][o]
  __shared__ float Bs[16][64];   // [c][k]
  const int tid = threadIdx.x, tx = tid & 15, ty = tid >> 4;
  const int n0 = blockIdx.x * 64, m0 = blockIdx.y * 64;
  const int am = tid >> 2, ak = (tid & 3) * 4;
  const int br = tid >> 4, bc4 = (tid & 15) * 4;
  float acc[4][4] = {};
  for (int k0 = 0; k0 < C; k0 += 16){
    float4 wv = *(const float4*)&W[(size_t)(m0+am)*C + k0 + ak];
    As[ak+0][am] = wv.x; As[ak+1][am] = wv.y; As[ak+2][am] = wv.z; As[ak+3][am] = wv.w;
    float4 xv = *(const float4*)&X[(size_t)(k0+br)*HW + n0 + bc4];
    if (use_mvn){
      float2 st = stats[k0+br];
      xv.x = (xv.x - st.x)*st.y; xv.y = (xv.y - st.x)*st.y;
      xv.z = (xv.z - st.x)*st.y; xv.w = (xv.w - st.x)*st.y;
    }
    *(float4*)&Bs[br][bc4] = xv;
    __syncthreads();
    mm16(As, Bs, acc, ty, tx);
    __syncthreads();
  }
  #pragma unroll
  for (int i = 0; i < 4; ++i){
    float bv = bias[m0 + ty*4 + i];
    *(float4*)&out[(size_t)(m0+ty*4+i)*HW + n0 + tx*4] =
        make_float4(acc[i][0]+bv, acc[i][1]+bv, acc[i][2]+bv, acc[i][3]+bv);
  }
}

// T2[k,l] = sum_c Fq[c,k] * Gk[c,l]  (A,B fp32 [512][4096], out fp32 [4096][4096])
__global__ __launch_bounds__(256) void k_sgemm(const float* __restrict__ A,
                                               const float* __restrict__ Bm,
                                               float* __restrict__ out){
  __shared__ float As[16][64];
  __shared__ float Bs[16][64];
  const int tid = threadIdx.x, tx = tid & 15, ty = tid >> 4;
  const int n0 = blockIdx.x * 64, m0 = blockIdx.y * 64;
  const int r = tid >> 4, c4 = (tid & 15) * 4;
  float acc[4][4] = {};
  for (int k0 = 0; k0 < C; k0 += 16){
    *(float4*)&As[r][c4] = *(const float4*)&A [(size_t)(k0+r)*HW + m0 + c4];
    *(float4*)&Bs[r][c4] = *(const float4*)&Bm[(size_t)(k0+r)*HW + n0 + c4];
    __syncthreads();
    mm16(As, Bs, acc, ty, tx);
    __syncthreads();
  }
  #pragma unroll
  for (int i = 0; i < 4; ++i)
    *(float4*)&out[(size_t)(m0+ty*4+i)*HW + n0 + tx*4] =
        make_float4(acc[i][0], acc[i][1], acc[i][2], acc[i][3]);
}

// P[c,o] = sum_l style[c,l]*ins[l]*W1[o,l]   (NT, out fp32 [512][256])
__global__ __launch_bounds__(256) void k_pgemm(const float* __restrict__ style,
                                               const float* __restrict__ W1,
                                               const float* __restrict__ ins,
                                               float* __restrict__ P){
  __shared__ float As[16][64];   // [l][c]
  __shared__ float Bs[16][64];   // [l][o]
  const int tid = threadIdx.x, tx = tid & 15, ty = tid >> 4;
  const int n0 = blockIdx.x * 64, m0 = blockIdx.y * 64;
  const int am = tid >> 2, ak = (tid & 3) * 4;
  float acc[4][4] = {};
  for (int k0 = 0; k0 < HW; k0 += 16){
    float4 sv = *(const float4*)&style[(size_t)(m0+am)*HW + k0 + ak];
    float4 iv = *(const float4*)&ins[k0 + ak];
    As[ak+0][am] = sv.x*iv.x; As[ak+1][am] = sv.y*iv.y;
    As[ak+2][am] = sv.z*iv.z; As[ak+3][am] = sv.w*iv.w;
    float4 wv = *(const float4*)&W1[(size_t)(n0+am)*HW + k0 + ak];
    Bs[ak+0][am] = wv.x; Bs[ak+1][am] = wv.y; Bs[ak+2][am] = wv.z; Bs[ak+3][am] = wv.w;
    __syncthreads();
    mm16(As, Bs, acc, ty, tx);
    __syncthreads();
  }
  #pragma unroll
  for (int i = 0; i < 4; ++i)
    #pragma unroll
    for (int j = 0; j < 4; ++j)
      P[(size_t)(m0+ty*4+i)*HID + n0 + tx*4 + j] = acc[i][j];
}

// hmid[k,o] = lrelu( inc[k] * sum_c content[c,k]*P[c,o] + b1[o] )  out fp32 [4096][256]
__global__ __launch_bounds__(256) void k_hmid(const float* __restrict__ content,
                                              const float* __restrict__ P,
                                              const float* __restrict__ inc,
                                              const float* __restrict__ b1,
                                              float* __restrict__ hmid){
  __shared__ float As[16][64];
  __shared__ float Bs[16][64];
  const int tid = threadIdx.x, tx = tid & 15, ty = tid >> 4;
  const int n0 = blockIdx.x * 64, m0 = blockIdx.y * 64;
  const int r = tid >> 4, c4 = (tid & 15) * 4;
  float acc[4][4] = {};
  for (int k0 = 0; k0 < C; k0 += 16){
    *(float4*)&As[r][c4] = *(const float4*)&content[(size_t)(k0+r)*HW + m0 + c4];
    *(float4*)&Bs[r][c4] = *(const float4*)&P[(size_t)(k0+r)*HID + n0 + c4];
    __syncthreads();
    mm16(As, Bs, acc, ty, tx);
    __syncthreads();
  }
  #pragma unroll
  for (int i = 0; i < 4; ++i){
    float sc = inc[m0 + ty*4 + i];
    #pragma unroll
    for (int j = 0; j < 4; ++j){
      float h = acc[i][j]*sc + b1[n0 + tx*4 + j];
      h = (h > 0.f) ? h : 0.2f*h;
      hmid[(size_t)(m0+ty*4+i)*HID + n0 + tx*4 + j] = h;
    }
  }
}

// clamp[k] = 0.4 + 0.5*sigmoid( dot(hmid[k,:], W2) + b2 )
__global__ __launch_bounds__(256) void k_psi(const float* __restrict__ hmid,
                                             const float* __restrict__ W2,
                                             const float* __restrict__ b2,
                                             float* __restrict__ clampv){
  const int k = blockIdx.x, tid = threadIdx.x;
  __shared__ float red[256];
  red[tid] = hmid[(size_t)k*HID + tid] * W2[tid];
  __syncthreads();
  for (int o = 128; o > 0; o >>= 1){
    if (tid < o) red[tid] += red[tid+o];
    __syncthreads();
  }
  if (tid == 0){
    float z = red[0] + b2[0];
    float psi = 1.f/(1.f + expf(-z));
    clampv[k] = psi*0.5f + 0.4f;
  }
}

// row softmax of T2[k,:] then Sg = sigmoid(50*(S - clamp[k])) written bf16
// IN-PLACE into the first half of T2 row k (row fully read into regs first).
__global__ __launch_bounds__(256) void k_softgate(float* __restrict__ T2,
                                                  const float* __restrict__ clampv){
  const int k = blockIdx.x, tid = threadIdx.x;
  float* row = &T2[(size_t)k*HW];
  float vals[16];
  float mx = -3.4e38f;
  #pragma unroll
  for (int i = 0; i < 16; ++i){ vals[i] = row[tid + i*256]; mx = fmaxf(mx, vals[i]); }
  __shared__ float red[256];
  red[tid] = mx; __syncthreads();
  for (int o = 128; o > 0; o >>= 1){
    if (tid < o) red[tid] = fmaxf(red[tid], red[tid+o]);
    __syncthreads();
  }
  mx = red[0]; __syncthreads();
  float s = 0.f;
  #pragma unroll
  for (int i = 0; i < 16; ++i){ vals[i] = expf(vals[i] - mx); s += vals[i]; }
  red[tid] = s; __syncthreads();
  for (int o = 128; o > 0; o >>= 1){
    if (tid < o) red[tid] += red[tid+o];
    __syncthreads();
  }
  const float inv = 1.f / red[0];
  const float cv = clampv[k];
  u16* Sg = (u16*)row;   // in-place: bf16 row occupies first half of fp32 row
  #pragma unroll
  for (int i = 0; i < 16; ++i){
    float sg = 1.f/(1.f + expf(-50.f*(vals[i]*inv - cv)));
    Sg[tid + i*256] = f2bf(sg);
  }
}

// O1[c,k] = sum_l Hv[c,l] * Sg[k,l]  (Sg bf16, row stride 2*HW u16; K=4096)
__global__ __launch_bounds__(256) void k_ogemm(const float* __restrict__ Hv,
                                               const u16* __restrict__ Sg,
                                               float* __restrict__ O1){
  __shared__ float As[16][64];   // [l][c]
  __shared__ float Bs[16][64];   // [l][k]
  const int tid = threadIdx.x, tx = tid & 15, ty = tid >> 4;
  const int n0 = blockIdx.x * 64, m0 = blockIdx.y * 64;
  const int am = tid >> 2, ak = (tid & 3) * 4;
  float acc[4][4] = {};
  for (int k0 = 0; k0 < HW; k0 += 16){
    float4 hv = *(const float4*)&Hv[(size_t)(m0+am)*HW + k0 + ak];
    As[ak+0][am] = hv.x; As[ak+1][am] = hv.y; As[ak+2][am] = hv.z; As[ak+3][am] = hv.w;
    float4 sv = bf4(&Sg[(size_t)(n0+am)*2*HW + k0 + ak]);
    Bs[ak+0][am] = sv.x; Bs[ak+1][am] = sv.y; Bs[ak+2][am] = sv.z; Bs[ak+3][am] = sv.w;
    __syncthreads();
    mm16(As, Bs, acc, ty, tx);
    __syncthreads();
  }
  #pragma unroll
  for (int i = 0; i < 4; ++i)
    *(float4*)&O1[(size_t)(m0+ty*4+i)*HW + n0 + tx*4] =
        make_float4(acc[i][0], acc[i][1], acc[i][2], acc[i][3]);
}

// out[o,k] = sum_c Wout[o,c]*O1[c,k] + bout[o] + content[o,k]   (fp32 out)
__global__ __launch_bounds__(256) void k_outconv(const float* __restrict__ Wout,
                                                 const float* __restrict__ O1,
                                                 const float* __restrict__ bout,
                                                 const float* __restrict__ content,
                                                 float* __restrict__ out){
  __shared__ float As[16][64];
  __shared__ float Bs[16][64];
  const int tid = threadIdx.x, tx = tid & 15, ty = tid >> 4;
  const int n0 = blockIdx.x * 64, m0 = blockIdx.y * 64;
  const int am = tid >> 2, ak = (tid & 3) * 4;
  const int br = tid >> 4, bc4 = (tid & 15) * 4;
  float acc[4][4] = {};
  for (int k0 = 0; k0 < C; k0 += 16){
    float4 wv = *(const float4*)&Wout[(size_t)(m0+am)*C + k0 + ak];
    As[ak+0][am] = wv.x; As[ak+1][am] = wv.y; As[ak+2][am] = wv.z; As[ak+3][am] = wv.w;
    *(float4*)&Bs[br][bc4] = *(const float4*)&O1[(size_t)(k0+br)*HW + n0 + bc4];
    __syncthreads();
    mm16(As, Bs, acc, ty, tx);
    __syncthreads();
  }
  #pragma unroll
  for (int i = 0; i < 4; ++i){
    const int o = m0 + ty*4 + i;
    float bv = bout[o];
    float4 cv = *(const float4*)&content[(size_t)o*HW + n0 + tx*4];
    *(float4*)&out[(size_t)o*HW + n0 + tx*4] =
        make_float4(acc[i][0]+bv+cv.x, acc[i][1]+bv+cv.y,
                    acc[i][2]+bv+cv.z, acc[i][3]+bv+cv.w);
  }
}

extern "C" void kernel_launch(void* const* d_in, const int* in_sizes, int n_in,
                              void* d_out, int out_size, void* d_ws, size_t ws_size,
                              hipStream_t stream){
  const float* content = (const float*)d_in[0];
  const float* style   = (const float*)d_in[1];
  const float* Wf   = (const float*)d_in[2];  const float* bf   = (const float*)d_in[3];
  const float* Wg   = (const float*)d_in[4];  const float* bg   = (const float*)d_in[5];
  const float* Wh   = (const float*)d_in[6];  const float* bh   = (const float*)d_in[7];
  const float* Wout = (const float*)d_in[8];  const float* bout = (const float*)d_in[9];
  const float* W1   = (const float*)d_in[10]; const float* b1   = (const float*)d_in[11];
  const float* W2   = (const float*)d_in[12]; const float* b2   = (const float*)d_in[13];
  float* out = (float*)d_out;

  char* ws = (char*)d_ws;
  size_t off = 0;
  auto alloc = [&](size_t bytes)->void*{
    void* p = (void*)(ws + off);
    off += (bytes + 255) & ~(size_t)255;
    return p;
  };
  float2* statsC = (float2*)alloc((size_t)Bn*C*sizeof(float2));
  float2* statsS = (float2*)alloc((size_t)Bn*C*sizeof(float2));
  float*  inc    = (float*) alloc((size_t)Bn*HW*sizeof(float));
  float*  ins    = (float*) alloc((size_t)Bn*HW*sizeof(float));
  float*  clampv = (float*) alloc((size_t)Bn*HW*sizeof(float));
  float*  P      = (float*) alloc((size_t)C*HID*sizeof(float));     // per-b reuse
  float*  hmid   = (float*) alloc((size_t)HW*HID*sizeof(float));    // per-b reuse
  float*  Fq     = (float*) alloc((size_t)C*HW*sizeof(float));      // per-b reuse
  float*  Gk     = (float*) alloc((size_t)C*HW*sizeof(float));
  float*  Hv     = (float*) alloc((size_t)C*HW*sizeof(float));
  float*  O1     = (float*) alloc((size_t)C*HW*sizeof(float));
  float*  T2     = (float*) alloc((size_t)HW*HW*sizeof(float));     // 64 MB, per-b reuse (Sg in-place)
  (void)ws_size; (void)in_sizes; (void)n_in; (void)out_size;

  k_stats  <<<dim3(Bn*C, 2),      256, 0, stream>>>(content, style, statsC, statsS);
  k_pixnorm<<<dim3(HW/256, Bn, 2),256, 0, stream>>>(content, style, inc, ins);

  for (int b = 0; b < Bn; ++b){
    const float* cb   = content + (size_t)b*C*HW;
    const float* sb   = style   + (size_t)b*C*HW;
    const float* incb = inc + (size_t)b*HW;
    const float* insb = ins + (size_t)b*HW;
    float* clb = clampv + (size_t)b*HW;

    k_conv   <<<dim3(64, 8),  256, 0, stream>>>(Wf, cb, bf, statsC + (size_t)b*C, 1, Fq);
    k_conv   <<<dim3(64, 8),  256, 0, stream>>>(Wg, sb, bg, statsS + (size_t)b*C, 1, Gk);
    k_conv   <<<dim3(64, 8),  256, 0, stream>>>(Wh, sb, bh, statsS + (size_t)b*C, 0, Hv);
    k_pgemm  <<<dim3(4, 8),   256, 0, stream>>>(sb, W1, insb, P);
    k_hmid   <<<dim3(4, 64),  256, 0, stream>>>(cb, P, incb, b1, hmid);
    k_psi    <<<dim3(HW),     256, 0, stream>>>(hmid, W2, b2, clb);
    k_sgemm  <<<dim3(64, 64), 256, 0, stream>>>(Fq, Gk, T2);
    k_softgate<<<dim3(HW),    256, 0, stream>>>(T2, clb);
    k_ogemm  <<<dim3(64, 8),  256, 0, stream>>>(Hv, (const u16*)T2, O1);
    k_outconv<<<dim3(64, 8),  256, 0, stream>>>(Wout, O1, bout, cb, out + (size_t)b*C*HW);
  }
}

// Round 4
// 2274.927 us; speedup vs baseline: 1.8918x; 1.8918x over previous
//
#include <hip/hip_runtime.h>

typedef unsigned short u16;
typedef __attribute__((ext_vector_type(8))) short short8;   // 8 bf16 (4 VGPRs)
typedef __attribute__((ext_vector_type(4))) float f32x4;    // MFMA acc

static constexpr int Bn  = 4;
static constexpr int C   = 512;
static constexpr int HW  = 4096;
static constexpr int HID = 256;

__device__ __forceinline__ float bf2f(u16 u){
  union { unsigned int i; float f; } x; x.i = ((unsigned int)u) << 16; return x.f;
}
__device__ __forceinline__ u16 f2bf(float f){
  union { float f; unsigned int i; } x; x.f = f;
  return (u16)((x.i + 0x7fffu + ((x.i >> 16) & 1u)) >> 16);
}
__device__ __forceinline__ short8 ldg8(const u16* p){ return *(const short8*)p; }

// ---------------- MFMA core: 128x128 block, 4 waves, 4x4 16x16x32 frags -----
// A: M x K row-major bf16 (pitch pA), B: N x K row-major bf16 (pitch pB) -> NT
// SPLIT=true: A=Ah+Al, B=Bh+Bl, 3 passes (hh, h*l, l*h) for ~fp32 accuracy.
template<bool SPLIT>
__device__ __forceinline__ void mfma_core(const u16* __restrict__ Ah, const u16* __restrict__ Al, int pA,
                                          const u16* __restrict__ Bh, const u16* __restrict__ Bl, int pB,
                                          int K, f32x4 (&acc)[4][4]){
  const int lane = threadIdx.x & 63;
  const int fr = lane & 15;            // row within 16 (A) / col row (B)
  const int ko = (lane >> 4) * 8;      // k offset within 32
  const u16* pa  = Ah + (size_t)fr * pA + ko;
  const u16* pb  = Bh + (size_t)fr * pB + ko;
  const u16* pa2 = SPLIT ? (Al + (size_t)fr * pA + ko) : (const u16*)nullptr;
  const u16* pb2 = SPLIT ? (Bl + (size_t)fr * pB + ko) : (const u16*)nullptr;
  const size_t sA = (size_t)16 * pA, sB = (size_t)16 * pB;
  for (int k0 = 0; k0 < K; k0 += 32){
    short8 a[4], b[4];
    #pragma unroll
    for (int i = 0; i < 4; ++i){
      a[i] = ldg8(pa + i*sA + k0);
      b[i] = ldg8(pb + i*sB + k0);
    }
    #pragma unroll
    for (int i = 0; i < 4; ++i)
      #pragma unroll
      for (int j = 0; j < 4; ++j)
        acc[i][j] = __builtin_amdgcn_mfma_f32_16x16x32_bf16(a[i], b[j], acc[i][j], 0, 0, 0);
    if (SPLIT){
      short8 a2[4], b2[4];
      #pragma unroll
      for (int i = 0; i < 4; ++i){
        a2[i] = ldg8(pa2 + i*sA + k0);
        b2[i] = ldg8(pb2 + i*sB + k0);
      }
      #pragma unroll
      for (int i = 0; i < 4; ++i)
        #pragma unroll
        for (int j = 0; j < 4; ++j){
          acc[i][j] = __builtin_amdgcn_mfma_f32_16x16x32_bf16(a[i],  b2[j], acc[i][j], 0, 0, 0);
          acc[i][j] = __builtin_amdgcn_mfma_f32_16x16x32_bf16(a2[i], b[j],  acc[i][j], 0, 0, 0);
        }
    }
  }
}

struct TileCtx { int wm, wn, cn, rq; };
__device__ __forceinline__ TileCtx tctx(){
  TileCtx t;
  const int wave = threadIdx.x >> 6, lane = threadIdx.x & 63;
  t.wm = blockIdx.y * 128 + (wave & 1) * 64;
  t.wn = blockIdx.x * 128 + (wave >> 1) * 64;
  t.cn = lane & 15; t.rq = (lane >> 4) * 4;
  return t;
}
#define ACC_ZERO(acc) { _Pragma("unroll") for (int i=0;i<4;++i) _Pragma("unroll") for (int j=0;j<4;++j) _Pragma("unroll") for (int r=0;r<4;++r) acc[i][j][r]=0.f; }

// conv (split inputs) + bias[n] -> split bf16 output (hi/lo), row-major pitch pO
__global__ __launch_bounds__(256) void g_conv_split(const u16* __restrict__ Ah, const u16* __restrict__ Al, int pA,
                                                    const u16* __restrict__ Bh, const u16* __restrict__ Bl, int pB,
                                                    int K, const float* __restrict__ bias,
                                                    u16* __restrict__ Ohi, u16* __restrict__ Olo, int pO){
  TileCtx t = tctx();
  f32x4 acc[4][4]; ACC_ZERO(acc);
  mfma_core<true>(Ah + (size_t)t.wm*pA, Al + (size_t)t.wm*pA, pA,
                  Bh + (size_t)t.wn*pB, Bl + (size_t)t.wn*pB, pB, K, acc);
  #pragma unroll
  for (int fm = 0; fm < 4; ++fm)
    #pragma unroll
    for (int fn = 0; fn < 4; ++fn)
      #pragma unroll
      for (int r = 0; r < 4; ++r){
        int gm = t.wm + fm*16 + t.rq + r;
        int gn = t.wn + fn*16 + t.cn;
        float v = acc[fm][fn][r] + bias[gn];
        u16 h = f2bf(v);
        Ohi[(size_t)gm*pO + gn] = h;
        Olo[(size_t)gm*pO + gn] = f2bf(v - bf2f(h));
      }
}

// split GEMM -> fp32 out (score logits T2)
__global__ __launch_bounds__(256) void g_gemm_split_f32(const u16* __restrict__ Ah, const u16* __restrict__ Al, int pA,
                                                        const u16* __restrict__ Bh, const u16* __restrict__ Bl, int pB,
                                                        int K, float* __restrict__ O, int pO){
  TileCtx t = tctx();
  f32x4 acc[4][4]; ACC_ZERO(acc);
  mfma_core<true>(Ah + (size_t)t.wm*pA, Al + (size_t)t.wm*pA, pA,
                  Bh + (size_t)t.wn*pB, Bl + (size_t)t.wn*pB, pB, K, acc);
  #pragma unroll
  for (int fm = 0; fm < 4; ++fm)
    #pragma unroll
    for (int fn = 0; fn < 4; ++fn)
      #pragma unroll
      for (int r = 0; r < 4; ++r)
        O[(size_t)(t.wm + fm*16 + t.rq + r)*pO + t.wn + fn*16 + t.cn] = acc[fm][fn][r];
}

// plain GEMM + bias[m] -> bf16 out (Hv conv)
__global__ __launch_bounds__(256) void g_gemm_biasm_bf16(const u16* __restrict__ A, int pA,
                                                         const u16* __restrict__ B, int pB,
                                                         int K, const float* __restrict__ bias,
                                                         u16* __restrict__ O, int pO){
  TileCtx t = tctx();
  f32x4 acc[4][4]; ACC_ZERO(acc);
  mfma_core<false>(A + (size_t)t.wm*pA, nullptr, pA, B + (size_t)t.wn*pB, nullptr, pB, K, acc);
  #pragma unroll
  for (int fm = 0; fm < 4; ++fm)
    #pragma unroll
    for (int fn = 0; fn < 4; ++fn)
      #pragma unroll
      for (int r = 0; r < 4; ++r){
        int gm = t.wm + fm*16 + t.rq + r;
        O[(size_t)gm*pO + t.wn + fn*16 + t.cn] = f2bf(acc[fm][fn][r] + bias[gm]);
      }
}

// plain GEMM, no bias -> bf16 out (ogemm O1T, pgemm PT)
__global__ __launch_bounds__(256) void g_gemm_bf16(const u16* __restrict__ A, int pA,
                                                   const u16* __restrict__ B, int pB,
                                                   int K, u16* __restrict__ O, int pO){
  TileCtx t = tctx();
  f32x4 acc[4][4]; ACC_ZERO(acc);
  mfma_core<false>(A + (size_t)t.wm*pA, nullptr, pA, B + (size_t)t.wn*pB, nullptr, pB, K, acc);
  #pragma unroll
  for (int fm = 0; fm < 4; ++fm)
    #pragma unroll
    for (int fn = 0; fn < 4; ++fn)
      #pragma unroll
      for (int r = 0; r < 4; ++r)
        O[(size_t)(t.wm + fm*16 + t.rq + r)*pO + t.wn + fn*16 + t.cn] = f2bf(acc[fm][fn][r]);
}

// out-conv: + bias[m] + residual[m][n] (fp32), fp32 out pitch HW
__global__ __launch_bounds__(256) void g_gemm_outconv(const u16* __restrict__ A, int pA,
                                                      const u16* __restrict__ B, int pB,
                                                      int K, const float* __restrict__ bias,
                                                      const float* __restrict__ res,
                                                      float* __restrict__ O){
  TileCtx t = tctx();
  f32x4 acc[4][4]; ACC_ZERO(acc);
  mfma_core<false>(A + (size_t)t.wm*pA, nullptr, pA, B + (size_t)t.wn*pB, nullptr, pB, K, acc);
  #pragma unroll
  for (int fm = 0; fm < 4; ++fm)
    #pragma unroll
    for (int fn = 0; fn < 4; ++fn)
      #pragma unroll
      for (int r = 0; r < 4; ++r){
        int gm = t.wm + fm*16 + t.rq + r;
        int gn = t.wn + fn*16 + t.cn;
        O[(size_t)gm*HW + gn] = acc[fm][fn][r] + bias[gm] + res[(size_t)gm*HW + gn];
      }
}

// hmid: lrelu(acc*inc[m] + b1[n]) -> fp32 out pitch HID
__global__ __launch_bounds__(256) void g_gemm_hmid(const u16* __restrict__ A, int pA,
                                                   const u16* __restrict__ B, int pB,
                                                   int K, const float* __restrict__ inc,
                                                   const float* __restrict__ b1,
                                                   float* __restrict__ O){
  TileCtx t = tctx();
  f32x4 acc[4][4]; ACC_ZERO(acc);
  mfma_core<false>(A + (size_t)t.wm*pA, nullptr, pA, B + (size_t)t.wn*pB, nullptr, pB, K, acc);
  #pragma unroll
  for (int fm = 0; fm < 4; ++fm)
    #pragma unroll
    for (int fn = 0; fn < 4; ++fn)
      #pragma unroll
      for (int r = 0; r < 4; ++r){
        int gm = t.wm + fm*16 + t.rq + r;
        int gn = t.wn + fn*16 + t.cn;
        float h = acc[fm][fn][r] * inc[gm] + b1[gn];
        O[(size_t)gm*HID + gn] = (h > 0.f) ? h : 0.2f*h;
      }
}

// ---------------- prep kernels ----------------------------------------------
// per (b,c): mean + rstd over spatial (unbiased var, eps 1e-5)
__global__ __launch_bounds__(256) void k_stats(const float* __restrict__ content,
                                               const float* __restrict__ style,
                                               float2* __restrict__ statsC,
                                               float2* __restrict__ statsS){
  const int bc = blockIdx.x;
  const float* X = (blockIdx.y == 0 ? content : style) + (size_t)bc * HW;
  float s = 0.f, sq = 0.f;
  for (int i = threadIdx.x; i < HW; i += 256){ float v = X[i]; s += v; sq += v*v; }
  __shared__ float rs[256], rq[256];
  rs[threadIdx.x] = s; rq[threadIdx.x] = sq; __syncthreads();
  for (int o = 128; o > 0; o >>= 1){
    if (threadIdx.x < o){ rs[threadIdx.x] += rs[threadIdx.x+o]; rq[threadIdx.x] += rq[threadIdx.x+o]; }
    __syncthreads();
  }
  if (threadIdx.x == 0){
    float mean = rs[0] / (float)HW;
    float var  = (rq[0] - rs[0]*mean) / (float)(HW - 1);
    (blockIdx.y == 0 ? statsC : statsS)[bc] = make_float2(mean, rsqrtf(var + 1e-5f));
  }
}

// per (tensor,b,k): 1/max(||x[:,k]||,1e-12)
__global__ __launch_bounds__(256) void k_pixnorm(const float* __restrict__ content,
                                                 const float* __restrict__ style,
                                                 float* __restrict__ inc,
                                                 float* __restrict__ ins){
  const int b = blockIdx.y;
  const int k = blockIdx.x * 256 + threadIdx.x;
  const float* X = (blockIdx.z == 0 ? content : style) + (size_t)b * C * HW + k;
  float acc = 0.f;
  for (int c = 0; c < C; ++c){ float v = X[(size_t)c * HW]; acc += v*v; }
  (blockIdx.z == 0 ? inc : ins)[b*HW + k] = 1.f / fmaxf(sqrtf(acc), 1e-12f);
}

// transpose X[C][HW] -> XT[HW][C]: mvn split (hi,lo) + raw bf16
__global__ __launch_bounds__(256) void k_prep(const float* __restrict__ X,
                                              const float2* __restrict__ stats,
                                              u16* __restrict__ Thi, u16* __restrict__ Tlo,
                                              u16* __restrict__ Traw){
  __shared__ float tile[64][65];
  __shared__ float2 st[64];
  const int k0 = blockIdx.x*64, c0 = blockIdx.y*64;
  const int t = threadIdx.x;
  if (t < 64) st[t] = stats[c0 + t];
  const int j4 = (t & 15) * 4, i0 = t >> 4;
  for (int r = 0; r < 4; ++r){
    int i = i0 + r*16;
    float4 v = *(const float4*)&X[(size_t)(c0+i)*HW + k0 + j4];
    tile[i][j4+0] = v.x; tile[i][j4+1] = v.y; tile[i][j4+2] = v.z; tile[i][j4+3] = v.w;
  }
  __syncthreads();
  const int kk = t >> 2, cc = (t & 3) * 16;
  u16 h[16], l[16], rw[16];
  #pragma unroll
  for (int q = 0; q < 16; ++q){
    float x = tile[cc+q][kk];
    float2 s = st[cc+q];
    rw[q] = f2bf(x);
    float v = (x - s.x) * s.y;
    h[q] = f2bf(v);
    l[q] = f2bf(v - bf2f(h[q]));
  }
  size_t o = (size_t)(k0+kk)*C + c0 + cc;
  #pragma unroll
  for (int q = 0; q < 16; ++q){ Thi[o+q] = h[q]; Tlo[o+q] = l[q]; Traw[o+q] = rw[q]; }
}

// styleS[c][l] = bf16(style[c,l]*ins[l])
__global__ __launch_bounds__(256) void k_scaleS(const float* __restrict__ style,
                                                const float* __restrict__ ins,
                                                u16* __restrict__ out){
  const size_t idx = ((size_t)blockIdx.x*256 + threadIdx.x) * 4;
  const int l = (int)(idx % HW);
  float4 v = *(const float4*)&style[idx];
  float4 s = *(const float4*)&ins[l];
  out[idx+0] = f2bf(v.x*s.x); out[idx+1] = f2bf(v.y*s.y);
  out[idx+2] = f2bf(v.z*s.z); out[idx+3] = f2bf(v.w*s.w);
}

// weight prep: split Wf,Wg ; bf16 Wh,Wout,W1
__global__ __launch_bounds__(256) void k_wprep(const float* __restrict__ Wf, const float* __restrict__ Wg,
                                               const float* __restrict__ Wh, const float* __restrict__ Wo,
                                               const float* __restrict__ W1,
                                               u16* __restrict__ Wfh, u16* __restrict__ Wfl,
                                               u16* __restrict__ Wgh, u16* __restrict__ Wgl,
                                               u16* __restrict__ Whb, u16* __restrict__ Wob,
                                               u16* __restrict__ W1b){
  const int idx = (blockIdx.x*256 + threadIdx.x) * 4;
  const int mode = blockIdx.y;
  const int nsmall = C*C;
  if (mode == 4){
    float4 v = *(const float4*)&W1[idx];
    W1b[idx+0]=f2bf(v.x); W1b[idx+1]=f2bf(v.y); W1b[idx+2]=f2bf(v.z); W1b[idx+3]=f2bf(v.w);
    return;
  }
  if (idx >= nsmall) return;
  const float* src = (mode==0)?Wf:(mode==1)?Wg:(mode==2)?Wh:Wo;
  float4 v = *(const float4*)&src[idx];
  float vv[4] = {v.x, v.y, v.z, v.w};
  if (mode <= 1){
    u16* oh = (mode==0)?Wfh:Wgh;  u16* ol = (mode==0)?Wfl:Wgl;
    #pragma unroll
    for (int q = 0; q < 4; ++q){
      u16 hh = f2bf(vv[q]);
      oh[idx+q] = hh; ol[idx+q] = f2bf(vv[q] - bf2f(hh));
    }
  } else {
    u16* ob = (mode==2)?Whb:Wob;
    #pragma unroll
    for (int q = 0; q < 4; ++q) ob[idx+q] = f2bf(vv[q]);
  }
}

// clamp[k] = 0.4 + 0.5*sigmoid(dot(hmid[k,:],W2)+b2)
__global__ __launch_bounds__(256) void k_psi(const float* __restrict__ hmid,
                                             const float* __restrict__ W2,
                                             const float* __restrict__ b2,
                                             float* __restrict__ clampv){
  const int k = blockIdx.x, tid = threadIdx.x;
  __shared__ float red[256];
  red[tid] = hmid[(size_t)k*HID + tid] * W2[tid];
  __syncthreads();
  for (int o = 128; o > 0; o >>= 1){
    if (tid < o) red[tid] += red[tid+o];
    __syncthreads();
  }
  if (tid == 0){
    float psi = 1.f/(1.f + expf(-(red[0] + b2[0])));
    clampv[k] = psi*0.5f + 0.4f;
  }
}

// row softmax of T2[k,:] then sigmoid(50*(S-clamp)) -> bf16 in-place (row head)
__global__ __launch_bounds__(256) void k_softgate(float* __restrict__ T2,
                                                  const float* __restrict__ clampv){
  const int k = blockIdx.x, tid = threadIdx.x;
  float* row = &T2[(size_t)k*HW];
  float vals[16];
  float mx = -3.4e38f;
  #pragma unroll
  for (int i = 0; i < 16; ++i){ vals[i] = row[tid + i*256]; mx = fmaxf(mx, vals[i]); }
  __shared__ float red[256];
  red[tid] = mx; __syncthreads();
  for (int o = 128; o > 0; o >>= 1){
    if (tid < o) red[tid] = fmaxf(red[tid], red[tid+o]);
    __syncthreads();
  }
  mx = red[0]; __syncthreads();
  float s = 0.f;
  #pragma unroll
  for (int i = 0; i < 16; ++i){ vals[i] = expf(vals[i] - mx); s += vals[i]; }
  red[tid] = s; __syncthreads();
  for (int o = 128; o > 0; o >>= 1){
    if (tid < o) red[tid] += red[tid+o];
    __syncthreads();
  }
  const float inv = 1.f / red[0];
  const float cv = clampv[k];
  u16* Sg = (u16*)row;
  #pragma unroll
  for (int i = 0; i < 16; ++i){
    float sg = 1.f/(1.f + expf(-50.f*(vals[i]*inv - cv)));
    Sg[tid + i*256] = f2bf(sg);
  }
}

extern "C" void kernel_launch(void* const* d_in, const int* in_sizes, int n_in,
                              void* d_out, int out_size, void* d_ws, size_t ws_size,
                              hipStream_t stream){
  const float* content = (const float*)d_in[0];
  const float* style   = (const float*)d_in[1];
  const float* Wf   = (const float*)d_in[2];  const float* bfv  = (const float*)d_in[3];
  const float* Wg   = (const float*)d_in[4];  const float* bg   = (const float*)d_in[5];
  const float* Wh   = (const float*)d_in[6];  const float* bh   = (const float*)d_in[7];
  const float* Wo   = (const float*)d_in[8];  const float* bout = (const float*)d_in[9];
  const float* W1   = (const float*)d_in[10]; const float* b1   = (const float*)d_in[11];
  const float* W2   = (const float*)d_in[12]; const float* b2   = (const float*)d_in[13];
  float* out = (float*)d_out;

  char* ws = (char*)d_ws;
  size_t off = 0;
  auto alloc = [&](size_t bytes)->void*{
    void* p = (void*)(ws + off);
    off += (bytes + 255) & ~(size_t)255;
    return p;
  };
  float2* statsC = (float2*)alloc((size_t)Bn*C*sizeof(float2));
  float2* statsS = (float2*)alloc((size_t)Bn*C*sizeof(float2));
  float*  inc    = (float*) alloc((size_t)Bn*HW*sizeof(float));
  float*  ins    = (float*) alloc((size_t)Bn*HW*sizeof(float));
  float*  clampv = (float*) alloc((size_t)Bn*HW*sizeof(float));
  u16* Wfh = (u16*)alloc((size_t)C*C*2), *Wfl = (u16*)alloc((size_t)C*C*2);
  u16* Wgh = (u16*)alloc((size_t)C*C*2), *Wgl = (u16*)alloc((size_t)C*C*2);
  u16* Whb = (u16*)alloc((size_t)C*C*2), *Wob = (u16*)alloc((size_t)C*C*2);
  u16* W1b = (u16*)alloc((size_t)HID*HW*2);
  u16* XcTh = (u16*)alloc((size_t)HW*C*2), *XcTl = (u16*)alloc((size_t)HW*C*2);
  u16* CrT  = (u16*)alloc((size_t)HW*C*2);
  u16* XsTh = (u16*)alloc((size_t)HW*C*2), *XsTl = (u16*)alloc((size_t)HW*C*2);
  u16* SrT  = (u16*)alloc((size_t)HW*C*2);
  u16* stS  = (u16*)alloc((size_t)C*HW*2);
  u16* FqTh = (u16*)alloc((size_t)HW*C*2), *FqTl = (u16*)alloc((size_t)HW*C*2);
  u16* GkTh = (u16*)alloc((size_t)HW*C*2), *GkTl = (u16*)alloc((size_t)HW*C*2);
  u16* Hvb  = (u16*)alloc((size_t)C*HW*2);
  u16* O1T  = (u16*)alloc((size_t)HW*C*2);
  u16* PT   = (u16*)alloc((size_t)HID*C*2);
  float* hmid = (float*)alloc((size_t)HW*HID*sizeof(float));
  float* T2   = (float*)alloc((size_t)HW*HW*sizeof(float));   // Sg bf16 in-place
  (void)ws_size; (void)in_sizes; (void)n_in; (void)out_size;

  k_stats  <<<dim3(Bn*C, 2),       256, 0, stream>>>(content, style, statsC, statsS);
  k_pixnorm<<<dim3(HW/256, Bn, 2), 256, 0, stream>>>(content, style, inc, ins);
  k_wprep  <<<dim3(HID*HW/1024, 5),256, 0, stream>>>(Wf, Wg, Wh, Wo, W1,
                                                     Wfh, Wfl, Wgh, Wgl, Whb, Wob, W1b);

  for (int b = 0; b < Bn; ++b){
    const float* cb = content + (size_t)b*C*HW;
    const float* sb = style   + (size_t)b*C*HW;
    const float* incb = inc + (size_t)b*HW;
    const float* insb = ins + (size_t)b*HW;
    float* clb = clampv + (size_t)b*HW;

    k_prep  <<<dim3(HW/64, C/64), 256, 0, stream>>>(cb, statsC + (size_t)b*C, XcTh, XcTl, CrT);
    k_prep  <<<dim3(HW/64, C/64), 256, 0, stream>>>(sb, statsS + (size_t)b*C, XsTh, XsTl, SrT);
    k_scaleS<<<dim3(C*HW/1024),   256, 0, stream>>>(sb, insb, stS);

    // FqT[k][o] = sum_c XcT[k,c]*Wf[o,c] + bf  (split in, split out)
    g_conv_split<<<dim3(C/128, HW/128), 256, 0, stream>>>(XcTh, XcTl, C, Wfh, Wfl, C, C, bfv, FqTh, FqTl, C);
    g_conv_split<<<dim3(C/128, HW/128), 256, 0, stream>>>(XsTh, XsTl, C, Wgh, Wgl, C, C, bg,  GkTh, GkTl, C);
    // Hv[c][l] = sum_c' Wh[c,c']*style[c',l] + bh   (A=Whb, B=SrT)
    g_gemm_biasm_bf16<<<dim3(HW/128, C/128), 256, 0, stream>>>(Whb, C, SrT, C, C, bh, Hvb, HW);
    // PT[o][c] = sum_l W1[o,l]*styleS[c,l]
    g_gemm_bf16<<<dim3(C/128, HID/128), 256, 0, stream>>>(W1b, HW, stS, HW, HW, PT, C);
    // hmid[k][o] = lrelu(inc[k]*sum_c CrT[k,c]*PT[o,c] + b1[o])
    g_gemm_hmid<<<dim3(HID/128, HW/128), 256, 0, stream>>>(CrT, C, PT, C, C, incb, b1, hmid);
    k_psi<<<dim3(HW), 256, 0, stream>>>(hmid, W2, b2, clb);
    // T2[k][l] = sum_o FqT[k,o]*GkT[l,o]
    g_gemm_split_f32<<<dim3(HW/128, HW/128), 256, 0, stream>>>(FqTh, FqTl, C, GkTh, GkTl, C, C, T2, HW);
    k_softgate<<<dim3(HW), 256, 0, stream>>>(T2, clb);
    // O1T[k][c] = sum_l Sg[k,l]*Hv[c,l]   (Sg bf16 rows at pitch 2*HW inside T2)
    g_gemm_bf16<<<dim3(C/128, HW/128), 256, 0, stream>>>((const u16*)T2, 2*HW, Hvb, HW, HW, O1T, C);
    // out[o][k] = sum_c Wout[o,c]*O1T[k,c] + bout[o] + content[o,k]
    g_gemm_outconv<<<dim3(HW/128, C/128), 256, 0, stream>>>(Wob, C, O1T, C, C, bout, cb, out + (size_t)b*C*HW);
  }
}

// Round 5
// 1599.234 us; speedup vs baseline: 2.6912x; 1.4225x over previous
//
#include <hip/hip_runtime.h>

typedef unsigned short u16;
typedef __attribute__((ext_vector_type(8))) short short8;   // 8 bf16 (4 VGPRs)
typedef __attribute__((ext_vector_type(4))) float f32x4;    // MFMA acc

static constexpr int Bn  = 4;
static constexpr int C   = 512;
static constexpr int HW  = 4096;
static constexpr int HID = 256;

__device__ __forceinline__ float bf2f(u16 u){
  union { unsigned int i; float f; } x; x.i = ((unsigned int)u) << 16; return x.f;
}
__device__ __forceinline__ u16 f2bf(float f){
  union { float f; unsigned int i; } x; x.f = f;
  return (u16)((x.i + 0x7fffu + ((x.i >> 16) & 1u)) >> 16);
}
__device__ __forceinline__ short8 ldg8(const u16* p){ return *(const short8*)p; }

// ---------------- MFMA core: 128x128 block tile, 4 waves, LDS-staged --------
// A: M x K row-major bf16 (pitch pA), B: N x K row-major bf16 (pitch pB) -> NT
// BK=32. Tile = 128 rows x 4 chunks of 16B. Thread t stages chunks t, t+256.
// SPLIT=true: A=Ah+Al, B=Bh+Bl, 3 passes (hh, h*l, l*h) for ~fp32 accuracy.
// lds must hold 4096*(SPLIT?4:2) u16. A/B pointers pre-offset to block tile.
template<bool SPLIT>
__device__ __forceinline__ void mfma_core(const u16* __restrict__ Ah, const u16* __restrict__ Al, int pA,
                                          const u16* __restrict__ Bh, const u16* __restrict__ Bl, int pB,
                                          int K, u16* lds, f32x4 (&acc)[4][4]){
  const int tid  = threadIdx.x;
  const int lane = tid & 63, wave = tid >> 6;
  const int fr = lane & 15, kq = lane >> 4;      // frag row / k-quad
  const int wm = (wave & 1) * 64, wn = (wave >> 1) * 64;
  u16* As  = lds;            // 8 KB
  u16* Bs  = lds + 4096;     // 8 KB
  u16* As2 = SPLIT ? lds + 8192  : nullptr;
  u16* Bs2 = SPLIT ? lds + 12288 : nullptr;
  const int c0 = tid, c1 = tid + 256;
  const int r0 = c0 >> 2, q0 = (c0 & 3) * 8;
  const int r1 = c1 >> 2, q1 = (c1 & 3) * 8;
  const size_t a0 = (size_t)r0*pA + q0, a1 = (size_t)r1*pA + q1;
  const size_t b0 = (size_t)r0*pB + q0, b1 = (size_t)r1*pB + q1;

  for (int k0 = 0; k0 < K; k0 += 32){
    // global loads for this slab (issue before barrier so latency overlaps wait)
    short8 va0 = ldg8(Ah + a0 + k0), va1 = ldg8(Ah + a1 + k0);
    short8 vb0 = ldg8(Bh + b0 + k0), vb1 = ldg8(Bh + b1 + k0);
    short8 ua0, ua1, ub0, ub1;
    if (SPLIT){
      ua0 = ldg8(Al + a0 + k0); ua1 = ldg8(Al + a1 + k0);
      ub0 = ldg8(Bl + b0 + k0); ub1 = ldg8(Bl + b1 + k0);
    }
    __syncthreads();           // previous iter's frag reads complete
    *(short8*)&As[c0*8] = va0; *(short8*)&As[c1*8] = va1;
    *(short8*)&Bs[c0*8] = vb0; *(short8*)&Bs[c1*8] = vb1;
    if (SPLIT){
      *(short8*)&As2[c0*8] = ua0; *(short8*)&As2[c1*8] = ua1;
      *(short8*)&Bs2[c0*8] = ub0; *(short8*)&Bs2[c1*8] = ub1;
    }
    __syncthreads();
    short8 a[4], b[4];
    #pragma unroll
    for (int i = 0; i < 4; ++i){
      a[i] = *(const short8*)&As[((wm + i*16 + fr)*4 + kq)*8];
      b[i] = *(const short8*)&Bs[((wn + i*16 + fr)*4 + kq)*8];
    }
    #pragma unroll
    for (int i = 0; i < 4; ++i)
      #pragma unroll
      for (int j = 0; j < 4; ++j)
        acc[i][j] = __builtin_amdgcn_mfma_f32_16x16x32_bf16(a[i], b[j], acc[i][j], 0, 0, 0);
    if (SPLIT){
      short8 a2[4], b2[4];
      #pragma unroll
      for (int i = 0; i < 4; ++i){
        a2[i] = *(const short8*)&As2[((wm + i*16 + fr)*4 + kq)*8];
        b2[i] = *(const short8*)&Bs2[((wn + i*16 + fr)*4 + kq)*8];
      }
      #pragma unroll
      for (int i = 0; i < 4; ++i)
        #pragma unroll
        for (int j = 0; j < 4; ++j){
          acc[i][j] = __builtin_amdgcn_mfma_f32_16x16x32_bf16(a[i],  b2[j], acc[i][j], 0, 0, 0);
          acc[i][j] = __builtin_amdgcn_mfma_f32_16x16x32_bf16(a2[i], b[j],  acc[i][j], 0, 0, 0);
        }
    }
  }
}

struct TileCtx { int wm, wn, cn, rq; };
__device__ __forceinline__ TileCtx tctx(){
  TileCtx t;
  const int wave = threadIdx.x >> 6, lane = threadIdx.x & 63;
  t.wm = blockIdx.y * 128 + (wave & 1) * 64;
  t.wn = blockIdx.x * 128 + (wave >> 1) * 64;
  t.cn = lane & 15; t.rq = (lane >> 4) * 4;
  return t;
}
#define ACC_ZERO(acc) { _Pragma("unroll") for (int i=0;i<4;++i) _Pragma("unroll") for (int j=0;j<4;++j) _Pragma("unroll") for (int r=0;r<4;++r) acc[i][j][r]=0.f; }

// conv (split inputs) + bias[n] -> split bf16 output (hi/lo), row-major pitch pO
__global__ __launch_bounds__(256) void g_conv_split(const u16* __restrict__ Ah, const u16* __restrict__ Al, int pA,
                                                    const u16* __restrict__ Bh, const u16* __restrict__ Bl, int pB,
                                                    int K, const float* __restrict__ bias,
                                                    u16* __restrict__ Ohi, u16* __restrict__ Olo, int pO){
  __shared__ u16 lds[16384];
  TileCtx t = tctx();
  f32x4 acc[4][4]; ACC_ZERO(acc);
  mfma_core<true>(Ah + (size_t)blockIdx.y*128*pA, Al + (size_t)blockIdx.y*128*pA, pA,
                  Bh + (size_t)blockIdx.x*128*pB, Bl + (size_t)blockIdx.x*128*pB, pB, K, lds, acc);
  #pragma unroll
  for (int fm = 0; fm < 4; ++fm)
    #pragma unroll
    for (int fn = 0; fn < 4; ++fn)
      #pragma unroll
      for (int r = 0; r < 4; ++r){
        int gm = t.wm + fm*16 + t.rq + r;
        int gn = t.wn + fn*16 + t.cn;
        float v = acc[fm][fn][r] + bias[gn];
        u16 h = f2bf(v);
        Ohi[(size_t)gm*pO + gn] = h;
        Olo[(size_t)gm*pO + gn] = f2bf(v - bf2f(h));
      }
}

// split GEMM -> fp32 out (score logits T2)
__global__ __launch_bounds__(256) void g_gemm_split_f32(const u16* __restrict__ Ah, const u16* __restrict__ Al, int pA,
                                                        const u16* __restrict__ Bh, const u16* __restrict__ Bl, int pB,
                                                        int K, float* __restrict__ O, int pO){
  __shared__ u16 lds[16384];
  TileCtx t = tctx();
  f32x4 acc[4][4]; ACC_ZERO(acc);
  mfma_core<true>(Ah + (size_t)blockIdx.y*128*pA, Al + (size_t)blockIdx.y*128*pA, pA,
                  Bh + (size_t)blockIdx.x*128*pB, Bl + (size_t)blockIdx.x*128*pB, pB, K, lds, acc);
  #pragma unroll
  for (int fm = 0; fm < 4; ++fm)
    #pragma unroll
    for (int fn = 0; fn < 4; ++fn)
      #pragma unroll
      for (int r = 0; r < 4; ++r)
        O[(size_t)(t.wm + fm*16 + t.rq + r)*pO + t.wn + fn*16 + t.cn] = acc[fm][fn][r];
}

// plain GEMM + bias[m] -> bf16 out (Hv conv)
__global__ __launch_bounds__(256) void g_gemm_biasm_bf16(const u16* __restrict__ A, int pA,
                                                         const u16* __restrict__ B, int pB,
                                                         int K, const float* __restrict__ bias,
                                                         u16* __restrict__ O, int pO){
  __shared__ u16 lds[8192];
  TileCtx t = tctx();
  f32x4 acc[4][4]; ACC_ZERO(acc);
  mfma_core<false>(A + (size_t)blockIdx.y*128*pA, nullptr, pA,
                   B + (size_t)blockIdx.x*128*pB, nullptr, pB, K, lds, acc);
  #pragma unroll
  for (int fm = 0; fm < 4; ++fm)
    #pragma unroll
    for (int fn = 0; fn < 4; ++fn)
      #pragma unroll
      for (int r = 0; r < 4; ++r){
        int gm = t.wm + fm*16 + t.rq + r;
        O[(size_t)gm*pO + t.wn + fn*16 + t.cn] = f2bf(acc[fm][fn][r] + bias[gm]);
      }
}

// plain GEMM, no bias -> bf16 out (ogemm O1T, pgemm PT)
__global__ __launch_bounds__(256) void g_gemm_bf16(const u16* __restrict__ A, int pA,
                                                   const u16* __restrict__ B, int pB,
                                                   int K, u16* __restrict__ O, int pO){
  __shared__ u16 lds[8192];
  TileCtx t = tctx();
  f32x4 acc[4][4]; ACC_ZERO(acc);
  mfma_core<false>(A + (size_t)blockIdx.y*128*pA, nullptr, pA,
                   B + (size_t)blockIdx.x*128*pB, nullptr, pB, K, lds, acc);
  #pragma unroll
  for (int fm = 0; fm < 4; ++fm)
    #pragma unroll
    for (int fn = 0; fn < 4; ++fn)
      #pragma unroll
      for (int r = 0; r < 4; ++r)
        O[(size_t)(t.wm + fm*16 + t.rq + r)*pO + t.wn + fn*16 + t.cn] = f2bf(acc[fm][fn][r]);
}

// out-conv: + bias[m] + residual[m][n] (fp32), fp32 out pitch HW
__global__ __launch_bounds__(256) void g_gemm_outconv(const u16* __restrict__ A, int pA,
                                                      const u16* __restrict__ B, int pB,
                                                      int K, const float* __restrict__ bias,
                                                      const float* __restrict__ res,
                                                      float* __restrict__ O){
  __shared__ u16 lds[8192];
  TileCtx t = tctx();
  f32x4 acc[4][4]; ACC_ZERO(acc);
  mfma_core<false>(A + (size_t)blockIdx.y*128*pA, nullptr, pA,
                   B + (size_t)blockIdx.x*128*pB, nullptr, pB, K, lds, acc);
  #pragma unroll
  for (int fm = 0; fm < 4; ++fm)
    #pragma unroll
    for (int fn = 0; fn < 4; ++fn)
      #pragma unroll
      for (int r = 0; r < 4; ++r){
        int gm = t.wm + fm*16 + t.rq + r;
        int gn = t.wn + fn*16 + t.cn;
        O[(size_t)gm*HW + gn] = acc[fm][fn][r] + bias[gm] + res[(size_t)gm*HW + gn];
      }
}

// hmid: lrelu(acc*inc[m] + b1[n]) -> fp32 out pitch HID
__global__ __launch_bounds__(256) void g_gemm_hmid(const u16* __restrict__ A, int pA,
                                                   const u16* __restrict__ B, int pB,
                                                   int K, const float* __restrict__ inc,
                                                   const float* __restrict__ b1,
                                                   float* __restrict__ O){
  __shared__ u16 lds[8192];
  TileCtx t = tctx();
  f32x4 acc[4][4]; ACC_ZERO(acc);
  mfma_core<false>(A + (size_t)blockIdx.y*128*pA, nullptr, pA,
                   B + (size_t)blockIdx.x*128*pB, nullptr, pB, K, lds, acc);
  #pragma unroll
  for (int fm = 0; fm < 4; ++fm)
    #pragma unroll
    for (int fn = 0; fn < 4; ++fn)
      #pragma unroll
      for (int r = 0; r < 4; ++r){
        int gm = t.wm + fm*16 + t.rq + r;
        int gn = t.wn + fn*16 + t.cn;
        float h = acc[fm][fn][r] * inc[gm] + b1[gn];
        O[(size_t)gm*HID + gn] = (h > 0.f) ? h : 0.2f*h;
      }
}

// ---------------- prep kernels ----------------------------------------------
__global__ __launch_bounds__(256) void k_stats(const float* __restrict__ content,
                                               const float* __restrict__ style,
                                               float2* __restrict__ statsC,
                                               float2* __restrict__ statsS){
  const int bc = blockIdx.x;
  const float* X = (blockIdx.y == 0 ? content : style) + (size_t)bc * HW;
  float s = 0.f, sq = 0.f;
  for (int i = threadIdx.x; i < HW; i += 256){ float v = X[i]; s += v; sq += v*v; }
  __shared__ float rs[256], rq[256];
  rs[threadIdx.x] = s; rq[threadIdx.x] = sq; __syncthreads();
  for (int o = 128; o > 0; o >>= 1){
    if (threadIdx.x < o){ rs[threadIdx.x] += rs[threadIdx.x+o]; rq[threadIdx.x] += rq[threadIdx.x+o]; }
    __syncthreads();
  }
  if (threadIdx.x == 0){
    float mean = rs[0] / (float)HW;
    float var  = (rq[0] - rs[0]*mean) / (float)(HW - 1);
    (blockIdx.y == 0 ? statsC : statsS)[bc] = make_float2(mean, rsqrtf(var + 1e-5f));
  }
}

__global__ __launch_bounds__(256) void k_pixnorm(const float* __restrict__ content,
                                                 const float* __restrict__ style,
                                                 float* __restrict__ inc,
                                                 float* __restrict__ ins){
  const int b = blockIdx.y;
  const int k = blockIdx.x * 256 + threadIdx.x;
  const float* X = (blockIdx.z == 0 ? content : style) + (size_t)b * C * HW + k;
  float acc = 0.f;
  for (int c = 0; c < C; ++c){ float v = X[(size_t)c * HW]; acc += v*v; }
  (blockIdx.z == 0 ? inc : ins)[b*HW + k] = 1.f / fmaxf(sqrtf(acc), 1e-12f);
}

// transpose X[C][HW] -> XT[HW][C]: mvn split (hi,lo) + raw bf16
__global__ __launch_bounds__(256) void k_prep(const float* __restrict__ X,
                                              const float2* __restrict__ stats,
                                              u16* __restrict__ Thi, u16* __restrict__ Tlo,
                                              u16* __restrict__ Traw){
  __shared__ float tile[64][65];
  __shared__ float2 st[64];
  const int k0 = blockIdx.x*64, c0 = blockIdx.y*64;
  const int t = threadIdx.x;
  if (t < 64) st[t] = stats[c0 + t];
  const int j4 = (t & 15) * 4, i0 = t >> 4;
  for (int r = 0; r < 4; ++r){
    int i = i0 + r*16;
    float4 v = *(const float4*)&X[(size_t)(c0+i)*HW + k0 + j4];
    tile[i][j4+0] = v.x; tile[i][j4+1] = v.y; tile[i][j4+2] = v.z; tile[i][j4+3] = v.w;
  }
  __syncthreads();
  const int kk = t >> 2, cc = (t & 3) * 16;
  u16 h[16], l[16], rw[16];
  #pragma unroll
  for (int q = 0; q < 16; ++q){
    float x = tile[cc+q][kk];
    float2 s = st[cc+q];
    rw[q] = f2bf(x);
    float v = (x - s.x) * s.y;
    h[q] = f2bf(v);
    l[q] = f2bf(v - bf2f(h[q]));
  }
  size_t o = (size_t)(k0+kk)*C + c0 + cc;
  #pragma unroll
  for (int q = 0; q < 16; ++q){ Thi[o+q] = h[q]; Tlo[o+q] = l[q]; Traw[o+q] = rw[q]; }
}

// styleS[c][l] = bf16(style[c,l]*ins[l])
__global__ __launch_bounds__(256) void k_scaleS(const float* __restrict__ style,
                                                const float* __restrict__ ins,
                                                u16* __restrict__ out){
  const size_t idx = ((size_t)blockIdx.x*256 + threadIdx.x) * 4;
  const int l = (int)(idx % HW);
  float4 v = *(const float4*)&style[idx];
  float4 s = *(const float4*)&ins[l];
  out[idx+0] = f2bf(v.x*s.x); out[idx+1] = f2bf(v.y*s.y);
  out[idx+2] = f2bf(v.z*s.z); out[idx+3] = f2bf(v.w*s.w);
}

// weight prep: split Wf,Wg ; bf16 Wh,Wout,W1
__global__ __launch_bounds__(256) void k_wprep(const float* __restrict__ Wf, const float* __restrict__ Wg,
                                               const float* __restrict__ Wh, const float* __restrict__ Wo,
                                               const float* __restrict__ W1,
                                               u16* __restrict__ Wfh, u16* __restrict__ Wfl,
                                               u16* __restrict__ Wgh, u16* __restrict__ Wgl,
                                               u16* __restrict__ Whb, u16* __restrict__ Wob,
                                               u16* __restrict__ W1b){
  const int idx = (blockIdx.x*256 + threadIdx.x) * 4;
  const int mode = blockIdx.y;
  const int nsmall = C*C;
  if (mode == 4){
    float4 v = *(const float4*)&W1[idx];
    W1b[idx+0]=f2bf(v.x); W1b[idx+1]=f2bf(v.y); W1b[idx+2]=f2bf(v.z); W1b[idx+3]=f2bf(v.w);
    return;
  }
  if (idx >= nsmall) return;
  const float* src = (mode==0)?Wf:(mode==1)?Wg:(mode==2)?Wh:Wo;
  float4 v = *(const float4*)&src[idx];
  float vv[4] = {v.x, v.y, v.z, v.w};
  if (mode <= 1){
    u16* oh = (mode==0)?Wfh:Wgh;  u16* ol = (mode==0)?Wfl:Wgl;
    #pragma unroll
    for (int q = 0; q < 4; ++q){
      u16 hh = f2bf(vv[q]);
      oh[idx+q] = hh; ol[idx+q] = f2bf(vv[q] - bf2f(hh));
    }
  } else {
    u16* ob = (mode==2)?Whb:Wob;
    #pragma unroll
    for (int q = 0; q < 4; ++q) ob[idx+q] = f2bf(vv[q]);
  }
}

// clamp[k] = 0.4 + 0.5*sigmoid(dot(hmid[k,:],W2)+b2)
__global__ __launch_bounds__(256) void k_psi(const float* __restrict__ hmid,
                                             const float* __restrict__ W2,
                                             const float* __restrict__ b2,
                                             float* __restrict__ clampv){
  const int k = blockIdx.x, tid = threadIdx.x;
  __shared__ float red[256];
  red[tid] = hmid[(size_t)k*HID + tid] * W2[tid];
  __syncthreads();
  for (int o = 128; o > 0; o >>= 1){
    if (tid < o) red[tid] += red[tid+o];
    __syncthreads();
  }
  if (tid == 0){
    float psi = 1.f/(1.f + expf(-(red[0] + b2[0])));
    clampv[k] = psi*0.5f + 0.4f;
  }
}

// row softmax of T2[k,:] then sigmoid(50*(S-clamp)) -> bf16 in-place (row head)
__global__ __launch_bounds__(256) void k_softgate(float* __restrict__ T2,
                                                  const float* __restrict__ clampv){
  const int k = blockIdx.x, tid = threadIdx.x;
  float* row = &T2[(size_t)k*HW];
  float vals[16];
  float mx = -3.4e38f;
  #pragma unroll
  for (int i = 0; i < 16; ++i){ vals[i] = row[tid + i*256]; mx = fmaxf(mx, vals[i]); }
  __shared__ float red[256];
  red[tid] = mx; __syncthreads();
  for (int o = 128; o > 0; o >>= 1){
    if (tid < o) red[tid] = fmaxf(red[tid], red[tid+o]);
    __syncthreads();
  }
  mx = red[0]; __syncthreads();
  float s = 0.f;
  #pragma unroll
  for (int i = 0; i < 16; ++i){ vals[i] = expf(vals[i] - mx); s += vals[i]; }
  red[tid] = s; __syncthreads();
  for (int o = 128; o > 0; o >>= 1){
    if (tid < o) red[tid] += red[tid+o];
    __syncthreads();
  }
  const float inv = 1.f / red[0];
  const float cv = clampv[k];
  u16* Sg = (u16*)row;
  #pragma unroll
  for (int i = 0; i < 16; ++i){
    float sg = 1.f/(1.f + expf(-50.f*(vals[i]*inv - cv)));
    Sg[tid + i*256] = f2bf(sg);
  }
}

extern "C" void kernel_launch(void* const* d_in, const int* in_sizes, int n_in,
                              void* d_out, int out_size, void* d_ws, size_t ws_size,
                              hipStream_t stream){
  const float* content = (const float*)d_in[0];
  const float* style   = (const float*)d_in[1];
  const float* Wf   = (const float*)d_in[2];  const float* bfv  = (const float*)d_in[3];
  const float* Wg   = (const float*)d_in[4];  const float* bg   = (const float*)d_in[5];
  const float* Wh   = (const float*)d_in[6];  const float* bh   = (const float*)d_in[7];
  const float* Wo   = (const float*)d_in[8];  const float* bout = (const float*)d_in[9];
  const float* W1   = (const float*)d_in[10]; const float* b1   = (const float*)d_in[11];
  const float* W2   = (const float*)d_in[12]; const float* b2   = (const float*)d_in[13];
  float* out = (float*)d_out;

  char* ws = (char*)d_ws;
  size_t off = 0;
  auto alloc = [&](size_t bytes)->void*{
    void* p = (void*)(ws + off);
    off += (bytes + 255) & ~(size_t)255;
    return p;
  };
  float2* statsC = (float2*)alloc((size_t)Bn*C*sizeof(float2));
  float2* statsS = (float2*)alloc((size_t)Bn*C*sizeof(float2));
  float*  inc    = (float*) alloc((size_t)Bn*HW*sizeof(float));
  float*  ins    = (float*) alloc((size_t)Bn*HW*sizeof(float));
  float*  clampv = (float*) alloc((size_t)Bn*HW*sizeof(float));
  u16* Wfh = (u16*)alloc((size_t)C*C*2), *Wfl = (u16*)alloc((size_t)C*C*2);
  u16* Wgh = (u16*)alloc((size_t)C*C*2), *Wgl = (u16*)alloc((size_t)C*C*2);
  u16* Whb = (u16*)alloc((size_t)C*C*2), *Wob = (u16*)alloc((size_t)C*C*2);
  u16* W1b = (u16*)alloc((size_t)HID*HW*2);
  u16* XcTh = (u16*)alloc((size_t)HW*C*2), *XcTl = (u16*)alloc((size_t)HW*C*2);
  u16* CrT  = (u16*)alloc((size_t)HW*C*2);
  u16* XsTh = (u16*)alloc((size_t)HW*C*2), *XsTl = (u16*)alloc((size_t)HW*C*2);
  u16* SrT  = (u16*)alloc((size_t)HW*C*2);
  u16* stS  = (u16*)alloc((size_t)C*HW*2);
  u16* FqTh = (u16*)alloc((size_t)HW*C*2), *FqTl = (u16*)alloc((size_t)HW*C*2);
  u16* GkTh = (u16*)alloc((size_t)HW*C*2), *GkTl = (u16*)alloc((size_t)HW*C*2);
  u16* Hvb  = (u16*)alloc((size_t)C*HW*2);
  u16* O1T  = (u16*)alloc((size_t)HW*C*2);
  u16* PT   = (u16*)alloc((size_t)HID*C*2);
  float* hmid = (float*)alloc((size_t)HW*HID*sizeof(float));
  float* T2   = (float*)alloc((size_t)HW*HW*sizeof(float));   // Sg bf16 in-place
  (void)ws_size; (void)in_sizes; (void)n_in; (void)out_size;

  k_stats  <<<dim3(Bn*C, 2),       256, 0, stream>>>(content, style, statsC, statsS);
  k_pixnorm<<<dim3(HW/256, Bn, 2), 256, 0, stream>>>(content, style, inc, ins);
  k_wprep  <<<dim3(HID*HW/1024, 5),256, 0, stream>>>(Wf, Wg, Wh, Wo, W1,
                                                     Wfh, Wfl, Wgh, Wgl, Whb, Wob, W1b);

  for (int b = 0; b < Bn; ++b){
    const float* cb = content + (size_t)b*C*HW;
    const float* sb = style   + (size_t)b*C*HW;
    const float* incb = inc + (size_t)b*HW;
    const float* insb = ins + (size_t)b*HW;
    float* clb = clampv + (size_t)b*HW;

    k_prep  <<<dim3(HW/64, C/64), 256, 0, stream>>>(cb, statsC + (size_t)b*C, XcTh, XcTl, CrT);
    k_prep  <<<dim3(HW/64, C/64), 256, 0, stream>>>(sb, statsS + (size_t)b*C, XsTh, XsTl, SrT);
    k_scaleS<<<dim3(C*HW/1024),   256, 0, stream>>>(sb, insb, stS);

    // FqT[k][o] = sum_c XcT[k,c]*Wf[o,c] + bf  (split in, split out)
    g_conv_split<<<dim3(C/128, HW/128), 256, 0, stream>>>(XcTh, XcTl, C, Wfh, Wfl, C, C, bfv, FqTh, FqTl, C);
    g_conv_split<<<dim3(C/128, HW/128), 256, 0, stream>>>(XsTh, XsTl, C, Wgh, Wgl, C, C, bg,  GkTh, GkTl, C);
    // Hv[c][l] = sum_c' Wh[c,c']*style[c',l] + bh   (A=Whb, B=SrT)
    g_gemm_biasm_bf16<<<dim3(HW/128, C/128), 256, 0, stream>>>(Whb, C, SrT, C, C, bh, Hvb, HW);
    // PT[o][c] = sum_l W1[o,l]*styleS[c,l]
    g_gemm_bf16<<<dim3(C/128, HID/128), 256, 0, stream>>>(W1b, HW, stS, HW, HW, PT, C);
    // hmid[k][o] = lrelu(inc[k]*sum_c CrT[k,c]*PT[o,c] + b1[o])
    g_gemm_hmid<<<dim3(HID/128, HW/128), 256, 0, stream>>>(CrT, C, PT, C, C, incb, b1, hmid);
    k_psi<<<dim3(HW), 256, 0, stream>>>(hmid, W2, b2, clb);
    // T2[k][l] = sum_o FqT[k,o]*GkT[l,o]
    g_gemm_split_f32<<<dim3(HW/128, HW/128), 256, 0, stream>>>(FqTh, FqTl, C, GkTh, GkTl, C, C, T2, HW);
    k_softgate<<<dim3(HW), 256, 0, stream>>>(T2, clb);
    // O1T[k][c] = sum_l Sg[k,l]*Hv[c,l]   (Sg bf16 rows at pitch 2*HW inside T2)
    g_gemm_bf16<<<dim3(C/128, HW/128), 256, 0, stream>>>((const u16*)T2, 2*HW, Hvb, HW, HW, O1T, C);
    // out[o][k] = sum_c Wout[o,c]*O1T[k,c] + bout[o] + content[o,k]
    g_gemm_outconv<<<dim3(HW/128, C/128), 256, 0, stream>>>(Wob, C, O1T, C, C, bout, cb, out + (size_t)b*C*HW);
  }
}

// Round 6
// 1170.352 us; speedup vs baseline: 3.6774x; 1.3665x over previous
//
#include <hip/hip_runtime.h>

typedef unsigned short u16;
typedef __attribute__((ext_vector_type(8))) short short8;   // 8 bf16 (4 VGPRs)
typedef __attribute__((ext_vector_type(4))) float f32x4;    // MFMA acc

static constexpr int Bn  = 4;
static constexpr int C   = 512;
static constexpr int HW  = 4096;
static constexpr int HID = 256;

__device__ __forceinline__ float bf2f(u16 u){
  union { unsigned int i; float f; } x; x.i = ((unsigned int)u) << 16; return x.f;
}
__device__ __forceinline__ u16 f2bf(float f){
  union { float f; unsigned int i; } x; x.f = f;
  return (u16)((x.i + 0x7fffu + ((x.i >> 16) & 1u)) >> 16);
}
__device__ __forceinline__ short8 ldg8(const u16* p){ return *(const short8*)p; }

// ---------------- MFMA core: 128x128 block tile, 4 waves, LDS-staged --------
// A: M x K row-major bf16 (pitch pA), B: N x K row-major bf16 (pitch pB) -> NT
// BK=32. LDS layout is k-outer: slab[kq][row][8], kq in 0..3 (8 k each),
// row in 0..127 -> both ds_write_b128 staging and ds_read_b128 fragment reads
// are at the 8-deep bank floor (conflict-free).  [r5: row-major layout was
// 16 banks x 16 deep = 2x penalty, SQ_LDS_BANK_CONFLICT 2.1e6]
// SPLIT=true: A=Ah+Al, B=Bh+Bl, 3 passes (hh, h*l, l*h) for ~fp32 accuracy.
template<bool SPLIT>
__device__ __forceinline__ void mfma_core(const u16* __restrict__ Ah, const u16* __restrict__ Al, int pA,
                                          const u16* __restrict__ Bh, const u16* __restrict__ Bl, int pB,
                                          int K, u16* lds, f32x4 (&acc)[4][4]){
  const int tid  = threadIdx.x;
  const int lane = tid & 63, wave = tid >> 6;
  const int fr = lane & 15, kq = lane >> 4;      // frag row / k-quad
  const int wm = (wave & 1) * 64, wn = (wave >> 1) * 64;
  u16* As  = lds;            // 8 KB
  u16* Bs  = lds + 4096;     // 8 KB
  u16* As2 = SPLIT ? lds + 8192  : nullptr;
  u16* Bs2 = SPLIT ? lds + 12288 : nullptr;
  const int c0 = tid, c1 = tid + 256;
  const int r0 = c0 >> 2, q0 = (c0 & 3) * 8;
  const int r1 = c1 >> 2, q1 = (c1 & 3) * 8;
  const size_t a0 = (size_t)r0*pA + q0, a1 = (size_t)r1*pA + q1;
  const size_t b0 = (size_t)r0*pB + q0, b1 = (size_t)r1*pB + q1;
  const int w0 = ((c0 & 3)*128 + (c0 >> 2)) * 8;   // k-outer LDS chunk index
  const int w1 = ((c1 & 3)*128 + (c1 >> 2)) * 8;
  const int kqBase = kq * 128 * 8;

  for (int k0 = 0; k0 < K; k0 += 32){
    short8 va0 = ldg8(Ah + a0 + k0), va1 = ldg8(Ah + a1 + k0);
    short8 vb0 = ldg8(Bh + b0 + k0), vb1 = ldg8(Bh + b1 + k0);
    short8 ua0, ua1, ub0, ub1;
    if (SPLIT){
      ua0 = ldg8(Al + a0 + k0); ua1 = ldg8(Al + a1 + k0);
      ub0 = ldg8(Bl + b0 + k0); ub1 = ldg8(Bl + b1 + k0);
    }
    __syncthreads();           // previous iter's frag reads complete
    *(short8*)&As[w0] = va0; *(short8*)&As[w1] = va1;
    *(short8*)&Bs[w0] = vb0; *(short8*)&Bs[w1] = vb1;
    if (SPLIT){
      *(short8*)&As2[w0] = ua0; *(short8*)&As2[w1] = ua1;
      *(short8*)&Bs2[w0] = ub0; *(short8*)&Bs2[w1] = ub1;
    }
    __syncthreads();
    short8 a[4], b[4];
    #pragma unroll
    for (int i = 0; i < 4; ++i){
      a[i] = *(const short8*)&As[kqBase + (wm + i*16 + fr)*8];
      b[i] = *(const short8*)&Bs[kqBase + (wn + i*16 + fr)*8];
    }
    #pragma unroll
    for (int i = 0; i < 4; ++i)
      #pragma unroll
      for (int j = 0; j < 4; ++j)
        acc[i][j] = __builtin_amdgcn_mfma_f32_16x16x32_bf16(a[i], b[j], acc[i][j], 0, 0, 0);
    if (SPLIT){
      short8 a2[4], b2[4];
      #pragma unroll
      for (int i = 0; i < 4; ++i){
        a2[i] = *(const short8*)&As2[kqBase + (wm + i*16 + fr)*8];
        b2[i] = *(const short8*)&Bs2[kqBase + (wn + i*16 + fr)*8];
      }
      #pragma unroll
      for (int i = 0; i < 4; ++i)
        #pragma unroll
        for (int j = 0; j < 4; ++j){
          acc[i][j] = __builtin_amdgcn_mfma_f32_16x16x32_bf16(a[i],  b2[j], acc[i][j], 0, 0, 0);
          acc[i][j] = __builtin_amdgcn_mfma_f32_16x16x32_bf16(a2[i], b[j],  acc[i][j], 0, 0, 0);
        }
    }
  }
}

struct TileCtx { int wm, wn, cn, rq; };
__device__ __forceinline__ TileCtx tctx(){
  TileCtx t;
  const int wave = threadIdx.x >> 6, lane = threadIdx.x & 63;
  t.wm = blockIdx.y * 128 + (wave & 1) * 64;
  t.wn = blockIdx.x * 128 + (wave >> 1) * 64;
  t.cn = lane & 15; t.rq = (lane >> 4) * 4;
  return t;
}
#define ACC_ZERO(acc) { _Pragma("unroll") for (int i=0;i<4;++i) _Pragma("unroll") for (int j=0;j<4;++j) _Pragma("unroll") for (int r=0;r<4;++r) acc[i][j][r]=0.f; }

// merged Fq/Gk conv (z=0: content->Fq, z=1: style->Gk), split in/out + bias[n]
__global__ __launch_bounds__(256) void g_conv_split2(const u16* __restrict__ A0h, const u16* __restrict__ A0l,
                                                     const u16* __restrict__ A1h, const u16* __restrict__ A1l,
                                                     const u16* __restrict__ B0h, const u16* __restrict__ B0l,
                                                     const u16* __restrict__ B1h, const u16* __restrict__ B1l,
                                                     const float* __restrict__ bias0, const float* __restrict__ bias1,
                                                     u16* __restrict__ O0h, u16* __restrict__ O0l,
                                                     u16* __restrict__ O1h, u16* __restrict__ O1l){
  __shared__ u16 lds[16384];
  const int z = blockIdx.z;
  const u16* Ah = z ? A1h : A0h;  const u16* Al = z ? A1l : A0l;
  const u16* Bh = z ? B1h : B0h;  const u16* Bl = z ? B1l : B0l;
  const float* bias = z ? bias1 : bias0;
  u16* Ohi = z ? O1h : O0h;  u16* Olo = z ? O1l : O0l;
  TileCtx t = tctx();
  f32x4 acc[4][4]; ACC_ZERO(acc);
  mfma_core<true>(Ah + (size_t)blockIdx.y*128*C, Al + (size_t)blockIdx.y*128*C, C,
                  Bh + (size_t)blockIdx.x*128*C, Bl + (size_t)blockIdx.x*128*C, C, C, lds, acc);
  #pragma unroll
  for (int fm = 0; fm < 4; ++fm)
    #pragma unroll
    for (int fn = 0; fn < 4; ++fn)
      #pragma unroll
      for (int r = 0; r < 4; ++r){
        int gm = t.wm + fm*16 + t.rq + r;
        int gn = t.wn + fn*16 + t.cn;
        float v = acc[fm][fn][r] + bias[gn];
        u16 h = f2bf(v);
        Ohi[(size_t)gm*C + gn] = h;
        Olo[(size_t)gm*C + gn] = f2bf(v - bf2f(h));
      }
}

// split GEMM -> fp32 out (score logits T2)
__global__ __launch_bounds__(256) void g_gemm_split_f32(const u16* __restrict__ Ah, const u16* __restrict__ Al, int pA,
                                                        const u16* __restrict__ Bh, const u16* __restrict__ Bl, int pB,
                                                        int K, float* __restrict__ O, int pO){
  __shared__ u16 lds[16384];
  TileCtx t = tctx();
  f32x4 acc[4][4]; ACC_ZERO(acc);
  mfma_core<true>(Ah + (size_t)blockIdx.y*128*pA, Al + (size_t)blockIdx.y*128*pA, pA,
                  Bh + (size_t)blockIdx.x*128*pB, Bl + (size_t)blockIdx.x*128*pB, pB, K, lds, acc);
  #pragma unroll
  for (int fm = 0; fm < 4; ++fm)
    #pragma unroll
    for (int fn = 0; fn < 4; ++fn)
      #pragma unroll
      for (int r = 0; r < 4; ++r)
        O[(size_t)(t.wm + fm*16 + t.rq + r)*pO + t.wn + fn*16 + t.cn] = acc[fm][fn][r];
}

// plain GEMM + bias[m] -> bf16 out (Hv conv)
__global__ __launch_bounds__(256) void g_gemm_biasm_bf16(const u16* __restrict__ A, int pA,
                                                         const u16* __restrict__ B, int pB,
                                                         int K, const float* __restrict__ bias,
                                                         u16* __restrict__ O, int pO){
  __shared__ u16 lds[8192];
  TileCtx t = tctx();
  f32x4 acc[4][4]; ACC_ZERO(acc);
  mfma_core<false>(A + (size_t)blockIdx.y*128*pA, nullptr, pA,
                   B + (size_t)blockIdx.x*128*pB, nullptr, pB, K, lds, acc);
  #pragma unroll
  for (int fm = 0; fm < 4; ++fm)
    #pragma unroll
    for (int fn = 0; fn < 4; ++fn)
      #pragma unroll
      for (int r = 0; r < 4; ++r){
        int gm = t.wm + fm*16 + t.rq + r;
        O[(size_t)gm*pO + t.wn + fn*16 + t.cn] = f2bf(acc[fm][fn][r] + bias[gm]);
      }
}

// split-K GEMM -> fp32 partials [z][M][N] (ogemm, pgemm)
__global__ __launch_bounds__(256) void g_gemm_partial(const u16* __restrict__ A, int pA,
                                                      const u16* __restrict__ B, int pB,
                                                      int Kper, float* __restrict__ O, int pO,
                                                      size_t sliceStride){
  __shared__ u16 lds[8192];
  TileCtx t = tctx();
  const int koff = blockIdx.z * Kper;
  f32x4 acc[4][4]; ACC_ZERO(acc);
  mfma_core<false>(A + (size_t)blockIdx.y*128*pA + koff, nullptr, pA,
                   B + (size_t)blockIdx.x*128*pB + koff, nullptr, pB, Kper, lds, acc);
  float* Oz = O + (size_t)blockIdx.z * sliceStride;
  #pragma unroll
  for (int fm = 0; fm < 4; ++fm)
    #pragma unroll
    for (int fn = 0; fn < 4; ++fn)
      #pragma unroll
      for (int r = 0; r < 4; ++r)
        Oz[(size_t)(t.wm + fm*16 + t.rq + r)*pO + t.wn + fn*16 + t.cn] = acc[fm][fn][r];
}

// reduce S fp32 partials -> bf16 (4 elems/thread)
__global__ __launch_bounds__(256) void k_reduce(const float* __restrict__ in, size_t sliceStride,
                                                int S, u16* __restrict__ out){
  const size_t i4 = ((size_t)blockIdx.x*256 + threadIdx.x) * 4;
  float4 s = *(const float4*)&in[i4];
  for (int z = 1; z < S; ++z){
    float4 v = *(const float4*)&in[(size_t)z*sliceStride + i4];
    s.x += v.x; s.y += v.y; s.z += v.z; s.w += v.w;
  }
  u16 r0 = f2bf(s.x), r1 = f2bf(s.y), r2 = f2bf(s.z), r3 = f2bf(s.w);
  uint2 uo; uo.x = (unsigned)r0 | ((unsigned)r1 << 16);
  uo.y = (unsigned)r2 | ((unsigned)r3 << 16);
  *(uint2*)&out[i4] = uo;
}

// out-conv: + bias[m] + residual[m][n] (fp32), fp32 out pitch HW
__global__ __launch_bounds__(256) void g_gemm_outconv(const u16* __restrict__ A, int pA,
                                                      const u16* __restrict__ B, int pB,
                                                      int K, const float* __restrict__ bias,
                                                      const float* __restrict__ res,
                                                      float* __restrict__ O){
  __shared__ u16 lds[8192];
  TileCtx t = tctx();
  f32x4 acc[4][4]; ACC_ZERO(acc);
  mfma_core<false>(A + (size_t)blockIdx.y*128*pA, nullptr, pA,
                   B + (size_t)blockIdx.x*128*pB, nullptr, pB, K, lds, acc);
  #pragma unroll
  for (int fm = 0; fm < 4; ++fm)
    #pragma unroll
    for (int fn = 0; fn < 4; ++fn)
      #pragma unroll
      for (int r = 0; r < 4; ++r){
        int gm = t.wm + fm*16 + t.rq + r;
        int gn = t.wn + fn*16 + t.cn;
        O[(size_t)gm*HW + gn] = acc[fm][fn][r] + bias[gm] + res[(size_t)gm*HW + gn];
      }
}

// hmid: lrelu(acc*inc[m] + b1[n]) -> fp32 out pitch HID
__global__ __launch_bounds__(256) void g_gemm_hmid(const u16* __restrict__ A, int pA,
                                                   const u16* __restrict__ B, int pB,
                                                   int K, const float* __restrict__ inc,
                                                   const float* __restrict__ b1,
                                                   float* __restrict__ O){
  __shared__ u16 lds[8192];
  TileCtx t = tctx();
  f32x4 acc[4][4]; ACC_ZERO(acc);
  mfma_core<false>(A + (size_t)blockIdx.y*128*pA, nullptr, pA,
                   B + (size_t)blockIdx.x*128*pB, nullptr, pB, K, lds, acc);
  #pragma unroll
  for (int fm = 0; fm < 4; ++fm)
    #pragma unroll
    for (int fn = 0; fn < 4; ++fn)
      #pragma unroll
      for (int r = 0; r < 4; ++r){
        int gm = t.wm + fm*16 + t.rq + r;
        int gn = t.wn + fn*16 + t.cn;
        float h = acc[fm][fn][r] * inc[gm] + b1[gn];
        O[(size_t)gm*HID + gn] = (h > 0.f) ? h : 0.2f*h;
      }
}

// ---------------- prep kernels ----------------------------------------------
__global__ __launch_bounds__(256) void k_stats(const float* __restrict__ content,
                                               const float* __restrict__ style,
                                               float2* __restrict__ statsC,
                                               float2* __restrict__ statsS){
  const int bc = blockIdx.x;
  const float* X = (blockIdx.y == 0 ? content : style) + (size_t)bc * HW;
  float s = 0.f, sq = 0.f;
  for (int i = threadIdx.x; i < HW; i += 256){ float v = X[i]; s += v; sq += v*v; }
  __shared__ float rs[256], rq[256];
  rs[threadIdx.x] = s; rq[threadIdx.x] = sq; __syncthreads();
  for (int o = 128; o > 0; o >>= 1){
    if (threadIdx.x < o){ rs[threadIdx.x] += rs[threadIdx.x+o]; rq[threadIdx.x] += rq[threadIdx.x+o]; }
    __syncthreads();
  }
  if (threadIdx.x == 0){
    float mean = rs[0] / (float)HW;
    float var  = (rq[0] - rs[0]*mean) / (float)(HW - 1);
    (blockIdx.y == 0 ? statsC : statsS)[bc] = make_float2(mean, rsqrtf(var + 1e-5f));
  }
}

__global__ __launch_bounds__(256) void k_pixnorm(const float* __restrict__ content,
                                                 const float* __restrict__ style,
                                                 float* __restrict__ inc,
                                                 float* __restrict__ ins){
  const int b = blockIdx.y;
  const int k = blockIdx.x * 256 + threadIdx.x;
  const float* X = (blockIdx.z == 0 ? content : style) + (size_t)b * C * HW + k;
  float acc = 0.f;
  for (int c = 0; c < C; ++c){ float v = X[(size_t)c * HW]; acc += v*v; }
  (blockIdx.z == 0 ? inc : ins)[b*HW + k] = 1.f / fmaxf(sqrtf(acc), 1e-12f);
}

// transpose X[C][HW] -> XT[HW][C]: mvn split (hi,lo) + raw bf16
__global__ __launch_bounds__(256) void k_prep(const float* __restrict__ X,
                                              const float2* __restrict__ stats,
                                              u16* __restrict__ Thi, u16* __restrict__ Tlo,
                                              u16* __restrict__ Traw){
  __shared__ float tile[64][65];
  __shared__ float2 st[64];
  const int k0 = blockIdx.x*64, c0 = blockIdx.y*64;
  const int t = threadIdx.x;
  if (t < 64) st[t] = stats[c0 + t];
  const int j4 = (t & 15) * 4, i0 = t >> 4;
  for (int r = 0; r < 4; ++r){
    int i = i0 + r*16;
    float4 v = *(const float4*)&X[(size_t)(c0+i)*HW + k0 + j4];
    tile[i][j4+0] = v.x; tile[i][j4+1] = v.y; tile[i][j4+2] = v.z; tile[i][j4+3] = v.w;
  }
  __syncthreads();
  const int kk = t >> 2, cc = (t & 3) * 16;
  u16 h[16], l[16], rw[16];
  #pragma unroll
  for (int q = 0; q < 16; ++q){
    float x = tile[cc+q][kk];
    float2 s = st[cc+q];
    rw[q] = f2bf(x);
    float v = (x - s.x) * s.y;
    h[q] = f2bf(v);
    l[q] = f2bf(v - bf2f(h[q]));
  }
  size_t o = (size_t)(k0+kk)*C + c0 + cc;
  #pragma unroll
  for (int q = 0; q < 16; ++q){ Thi[o+q] = h[q]; Tlo[o+q] = l[q]; Traw[o+q] = rw[q]; }
}

// styleS[c][l] = bf16(style[c,l]*ins[l])
__global__ __launch_bounds__(256) void k_scaleS(const float* __restrict__ style,
                                                const float* __restrict__ ins,
                                                u16* __restrict__ out){
  const size_t idx = ((size_t)blockIdx.x*256 + threadIdx.x) * 4;
  const int l = (int)(idx % HW);
  float4 v = *(const float4*)&style[idx];
  float4 s = *(const float4*)&ins[l];
  out[idx+0] = f2bf(v.x*s.x); out[idx+1] = f2bf(v.y*s.y);
  out[idx+2] = f2bf(v.z*s.z); out[idx+3] = f2bf(v.w*s.w);
}

// weight prep: split Wf,Wg ; bf16 Wh,Wout,W1
__global__ __launch_bounds__(256) void k_wprep(const float* __restrict__ Wf, const float* __restrict__ Wg,
                                               const float* __restrict__ Wh, const float* __restrict__ Wo,
                                               const float* __restrict__ W1,
                                               u16* __restrict__ Wfh, u16* __restrict__ Wfl,
                                               u16* __restrict__ Wgh, u16* __restrict__ Wgl,
                                               u16* __restrict__ Whb, u16* __restrict__ Wob,
                                               u16* __restrict__ W1b){
  const int idx = (blockIdx.x*256 + threadIdx.x) * 4;
  const int mode = blockIdx.y;
  const int nsmall = C*C;
  if (mode == 4){
    float4 v = *(const float4*)&W1[idx];
    W1b[idx+0]=f2bf(v.x); W1b[idx+1]=f2bf(v.y); W1b[idx+2]=f2bf(v.z); W1b[idx+3]=f2bf(v.w);
    return;
  }
  if (idx >= nsmall) return;
  const float* src = (mode==0)?Wf:(mode==1)?Wg:(mode==2)?Wh:Wo;
  float4 v = *(const float4*)&src[idx];
  float vv[4] = {v.x, v.y, v.z, v.w};
  if (mode <= 1){
    u16* oh = (mode==0)?Wfh:Wgh;  u16* ol = (mode==0)?Wfl:Wgl;
    #pragma unroll
    for (int q = 0; q < 4; ++q){
      u16 hh = f2bf(vv[q]);
      oh[idx+q] = hh; ol[idx+q] = f2bf(vv[q] - bf2f(hh));
    }
  } else {
    u16* ob = (mode==2)?Whb:Wob;
    #pragma unroll
    for (int q = 0; q < 4; ++q) ob[idx+q] = f2bf(vv[q]);
  }
}

// clamp[k] = 0.4 + 0.5*sigmoid(dot(hmid[k,:],W2)+b2)
__global__ __launch_bounds__(256) void k_psi(const float* __restrict__ hmid,
                                             const float* __restrict__ W2,
                                             const float* __restrict__ b2,
                                             float* __restrict__ clampv){
  const int k = blockIdx.x, tid = threadIdx.x;
  __shared__ float red[256];
  red[tid] = hmid[(size_t)k*HID + tid] * W2[tid];
  __syncthreads();
  for (int o = 128; o > 0; o >>= 1){
    if (tid < o) red[tid] += red[tid+o];
    __syncthreads();
  }
  if (tid == 0){
    float psi = 1.f/(1.f + expf(-(red[0] + b2[0])));
    clampv[k] = psi*0.5f + 0.4f;
  }
}

// row softmax of T2[k,:] then sigmoid(50*(S-clamp)) -> bf16 in-place (row head)
__global__ __launch_bounds__(256) void k_softgate(float* __restrict__ T2,
                                                  const float* __restrict__ clampv){
  const int k = blockIdx.x, tid = threadIdx.x;
  float* row = &T2[(size_t)k*HW];
  float vals[16];
  float mx = -3.4e38f;
  #pragma unroll
  for (int i = 0; i < 16; ++i){ vals[i] = row[tid + i*256]; mx = fmaxf(mx, vals[i]); }
  __shared__ float red[256];
  red[tid] = mx; __syncthreads();
  for (int o = 128; o > 0; o >>= 1){
    if (tid < o) red[tid] = fmaxf(red[tid], red[tid+o]);
    __syncthreads();
  }
  mx = red[0]; __syncthreads();
  float s = 0.f;
  #pragma unroll
  for (int i = 0; i < 16; ++i){ vals[i] = expf(vals[i] - mx); s += vals[i]; }
  red[tid] = s; __syncthreads();
  for (int o = 128; o > 0; o >>= 1){
    if (tid < o) red[tid] += red[tid+o];
    __syncthreads();
  }
  const float inv = 1.f / red[0];
  const float cv = clampv[k];
  u16* Sg = (u16*)row;
  #pragma unroll
  for (int i = 0; i < 16; ++i){
    float sg = 1.f/(1.f + expf(-50.f*(vals[i]*inv - cv)));
    Sg[tid + i*256] = f2bf(sg);
  }
}

extern "C" void kernel_launch(void* const* d_in, const int* in_sizes, int n_in,
                              void* d_out, int out_size, void* d_ws, size_t ws_size,
                              hipStream_t stream){
  const float* content = (const float*)d_in[0];
  const float* style   = (const float*)d_in[1];
  const float* Wf   = (const float*)d_in[2];  const float* bfv  = (const float*)d_in[3];
  const float* Wg   = (const float*)d_in[4];  const float* bg   = (const float*)d_in[5];
  const float* Wh   = (const float*)d_in[6];  const float* bh   = (const float*)d_in[7];
  const float* Wo   = (const float*)d_in[8];  const float* bout = (const float*)d_in[9];
  const float* W1   = (const float*)d_in[10]; const float* b1   = (const float*)d_in[11];
  const float* W2   = (const float*)d_in[12]; const float* b2   = (const float*)d_in[13];
  float* out = (float*)d_out;

  char* ws = (char*)d_ws;
  size_t off = 0;
  auto alloc = [&](size_t bytes)->void*{
    void* p = (void*)(ws + off);
    off += (bytes + 255) & ~(size_t)255;
    return p;
  };
  float2* statsC = (float2*)alloc((size_t)Bn*C*sizeof(float2));
  float2* statsS = (float2*)alloc((size_t)Bn*C*sizeof(float2));
  float*  inc    = (float*) alloc((size_t)Bn*HW*sizeof(float));
  float*  ins    = (float*) alloc((size_t)Bn*HW*sizeof(float));
  float*  clampv = (float*) alloc((size_t)Bn*HW*sizeof(float));
  u16* Wfh = (u16*)alloc((size_t)C*C*2), *Wfl = (u16*)alloc((size_t)C*C*2);
  u16* Wgh = (u16*)alloc((size_t)C*C*2), *Wgl = (u16*)alloc((size_t)C*C*2);
  u16* Whb = (u16*)alloc((size_t)C*C*2), *Wob = (u16*)alloc((size_t)C*C*2);
  u16* W1b = (u16*)alloc((size_t)HID*HW*2);
  u16* XcTh = (u16*)alloc((size_t)HW*C*2), *XcTl = (u16*)alloc((size_t)HW*C*2);
  u16* CrT  = (u16*)alloc((size_t)HW*C*2);
  u16* XsTh = (u16*)alloc((size_t)HW*C*2), *XsTl = (u16*)alloc((size_t)HW*C*2);
  u16* SrT  = (u16*)alloc((size_t)HW*C*2);
  u16* stS  = (u16*)alloc((size_t)C*HW*2);
  u16* FqTh = (u16*)alloc((size_t)HW*C*2), *FqTl = (u16*)alloc((size_t)HW*C*2);
  u16* GkTh = (u16*)alloc((size_t)HW*C*2), *GkTl = (u16*)alloc((size_t)HW*C*2);
  u16* Hvb  = (u16*)alloc((size_t)C*HW*2);
  u16* O1T  = (u16*)alloc((size_t)HW*C*2);
  u16* PT   = (u16*)alloc((size_t)HID*C*2);
  float* hmid  = (float*)alloc((size_t)HW*HID*sizeof(float));
  float* Ppart = (float*)alloc((size_t)16*HID*C*sizeof(float));   // 8 MB
  float* Opart = (float*)alloc((size_t)4*HW*C*sizeof(float));     // 32 MB
  float* T2    = (float*)alloc((size_t)HW*HW*sizeof(float));      // 64 MB (Sg in-place)
  (void)ws_size; (void)in_sizes; (void)n_in; (void)out_size;

  k_stats  <<<dim3(Bn*C, 2),       256, 0, stream>>>(content, style, statsC, statsS);
  k_pixnorm<<<dim3(HW/256, Bn, 2), 256, 0, stream>>>(content, style, inc, ins);
  k_wprep  <<<dim3(HID*HW/1024, 5),256, 0, stream>>>(Wf, Wg, Wh, Wo, W1,
                                                     Wfh, Wfl, Wgh, Wgl, Whb, Wob, W1b);

  for (int b = 0; b < Bn; ++b){
    const float* cb = content + (size_t)b*C*HW;
    const float* sb = style   + (size_t)b*C*HW;
    const float* incb = inc + (size_t)b*HW;
    const float* insb = ins + (size_t)b*HW;
    float* clb = clampv + (size_t)b*HW;

    k_prep  <<<dim3(HW/64, C/64), 256, 0, stream>>>(cb, statsC + (size_t)b*C, XcTh, XcTl, CrT);
    k_prep  <<<dim3(HW/64, C/64), 256, 0, stream>>>(sb, statsS + (size_t)b*C, XsTh, XsTl, SrT);
    k_scaleS<<<dim3(C*HW/1024),   256, 0, stream>>>(sb, insb, stS);

    // FqT/GkT in one launch: z=0 content->Fq (Wf), z=1 style->Gk (Wg)
    g_conv_split2<<<dim3(C/128, HW/128, 2), 256, 0, stream>>>(
        XcTh, XcTl, XsTh, XsTl, Wfh, Wfl, Wgh, Wgl, bfv, bg,
        FqTh, FqTl, GkTh, GkTl);
    // Hv[c][l] = sum_c' Wh[c,c']*style[c',l] + bh
    g_gemm_biasm_bf16<<<dim3(HW/128, C/128), 256, 0, stream>>>(Whb, C, SrT, C, C, bh, Hvb, HW);
    // PT[o][c] = sum_l W1[o,l]*styleS[c,l]  -- split-K 16 x 256
    g_gemm_partial<<<dim3(C/128, HID/128, 16), 256, 0, stream>>>(W1b, HW, stS, HW, 256,
                                                                 Ppart, C, (size_t)HID*C);
    k_reduce<<<dim3(HID*C/1024), 256, 0, stream>>>(Ppart, (size_t)HID*C, 16, PT);
    // hmid[k][o] = lrelu(inc[k]*sum_c CrT[k,c]*PT[o,c] + b1[o])
    g_gemm_hmid<<<dim3(HID/128, HW/128), 256, 0, stream>>>(CrT, C, PT, C, C, incb, b1, hmid);
    k_psi<<<dim3(HW), 256, 0, stream>>>(hmid, W2, b2, clb);
    // T2[k][l] = sum_o FqT[k,o]*GkT[l,o]
    g_gemm_split_f32<<<dim3(HW/128, HW/128), 256, 0, stream>>>(FqTh, FqTl, C, GkTh, GkTl, C, C, T2, HW);
    k_softgate<<<dim3(HW), 256, 0, stream>>>(T2, clb);
    // O1T[k][c] = sum_l Sg[k,l]*Hv[c,l]  -- split-K 4 x 1024 (Sg pitch 2*HW in T2)
    g_gemm_partial<<<dim3(C/128, HW/128, 4), 256, 0, stream>>>((const u16*)T2, 2*HW, Hvb, HW, 1024,
                                                               Opart, C, (size_t)HW*C);
    k_reduce<<<dim3(HW*C/1024), 256, 0, stream>>>(Opart, (size_t)HW*C, 4, O1T);
    // out[o][k] = sum_c Wout[o,c]*O1T[k,c] + bout[o] + content[o,k]
    g_gemm_outconv<<<dim3(HW/128, C/128), 256, 0, stream>>>(Wob, C, O1T, C, C, bout, cb, out + (size_t)b*C*HW);
  }
}

// Round 8
// 1111.793 us; speedup vs baseline: 3.8711x; 1.0527x over previous
//
#include <hip/hip_runtime.h>

typedef unsigned short u16;
typedef __attribute__((ext_vector_type(8))) short short8;   // 8 bf16 (4 VGPRs)
typedef __attribute__((ext_vector_type(4))) float f32x4;    // MFMA acc

static constexpr int Bn  = 4;
static constexpr int C   = 512;
static constexpr int HW  = 4096;
static constexpr int HID = 256;

__device__ __forceinline__ float bf2f(u16 u){
  union { unsigned int i; float f; } x; x.i = ((unsigned int)u) << 16; return x.f;
}
__device__ __forceinline__ u16 f2bf(float f){
  union { float f; unsigned int i; } x; x.f = f;
  return (u16)((x.i + 0x7fffu + ((x.i >> 16) & 1u)) >> 16);
}
// async global->LDS DMA, 16B per lane; lds dest = wave-uniform base + lane*16
__device__ __forceinline__ void gld16(const u16* g, u16* l){
  __builtin_amdgcn_global_load_lds((const __attribute__((address_space(1))) void*)g,
                                   (__attribute__((address_space(3))) void*)l, 16, 0, 0);
}

// ---------------- MFMA core: 128x128 block tile, 4 waves, DMA-staged --------
// A: M x K row-major bf16 (pitch pA), B: N x K row-major bf16 (pitch pB) -> NT
// BK=32. LDS slabs row-major [row][32] u16 (8KB each = 8 wave-DMA instrs of
// 1KB). Each wave stages 2 instrs/slab covering rows wave*32 + i*16 .. +15.
// [r7 BUG: wave*64 + 4 instrs = 16KB into an 8KB slab -> waves 2,3 clobbered
// Bs and read out-of-tile rows; absmax 7.4. Fixed: wave*32, i in {0,1}.]
// Lane l of instr i lands at slab byte (wave*32+i*16)*64 + l*16 (linear ✓);
// global side: row +(l>>2), k-chunk (l&3)*8 -> 64B contiguous per 4 lanes.
// SPLIT=true: A=Ah+Al, B=Bh+Bl, 3 passes (hh, h*l, l*h) for ~fp32 accuracy.
template<bool SPLIT>
__device__ __forceinline__ void mfma_core(const u16* __restrict__ Ah, const u16* __restrict__ Al, int pA,
                                          const u16* __restrict__ Bh, const u16* __restrict__ Bl, int pB,
                                          int K, u16* lds, f32x4 (&acc)[4][4]){
  const int tid  = threadIdx.x;
  const int lane = tid & 63, wave = tid >> 6;
  const int fr = lane & 15, kq = lane >> 4;      // frag row / k-quad
  const int wm = (wave & 1) * 64, wn = (wave >> 1) * 64;
  u16* As  = lds;            // 8 KB
  u16* Bs  = lds + 4096;     // 8 KB
  u16* As2 = SPLIT ? lds + 8192  : nullptr;
  u16* Bs2 = SPLIT ? lds + 12288 : nullptr;
  const int srow = wave*32 + (lane >> 2);        // staging row (+i*16), i in {0,1}
  const int sq   = (lane & 3) * 8;               // staging k-offset (u16)
  const size_t ga = (size_t)srow * pA + sq;
  const size_t gb = (size_t)srow * pB + sq;
  const int ldsc = wave * 1024;                  // wave chunk base (u16 idx)

  for (int k0 = 0; k0 < K; k0 += 32){
    __syncthreads();           // prior iter's frag reads done before DMA overwrites
    #pragma unroll
    for (int i = 0; i < 2; ++i){
      gld16(Ah + ga + (size_t)i*16*pA + k0, As + ldsc + i*512);
      gld16(Bh + gb + (size_t)i*16*pB + k0, Bs + ldsc + i*512);
      if (SPLIT){
        gld16(Al + ga + (size_t)i*16*pA + k0, As2 + ldsc + i*512);
        gld16(Bl + gb + (size_t)i*16*pB + k0, Bs2 + ldsc + i*512);
      }
    }
    __syncthreads();           // drains vmcnt(0) -> DMA data visible
    short8 a[4], b[4];
    #pragma unroll
    for (int i = 0; i < 4; ++i){
      a[i] = *(const short8*)&As[(wm + i*16 + fr)*32 + kq*8];
      b[i] = *(const short8*)&Bs[(wn + i*16 + fr)*32 + kq*8];
    }
    #pragma unroll
    for (int i = 0; i < 4; ++i)
      #pragma unroll
      for (int j = 0; j < 4; ++j)
        acc[i][j] = __builtin_amdgcn_mfma_f32_16x16x32_bf16(a[i], b[j], acc[i][j], 0, 0, 0);
    if (SPLIT){
      short8 a2[4], b2[4];
      #pragma unroll
      for (int i = 0; i < 4; ++i){
        a2[i] = *(const short8*)&As2[(wm + i*16 + fr)*32 + kq*8];
        b2[i] = *(const short8*)&Bs2[(wn + i*16 + fr)*32 + kq*8];
      }
      #pragma unroll
      for (int i = 0; i < 4; ++i)
        #pragma unroll
        for (int j = 0; j < 4; ++j){
          acc[i][j] = __builtin_amdgcn_mfma_f32_16x16x32_bf16(a[i],  b2[j], acc[i][j], 0, 0, 0);
          acc[i][j] = __builtin_amdgcn_mfma_f32_16x16x32_bf16(a2[i], b[j],  acc[i][j], 0, 0, 0);
        }
    }
  }
}

struct TileCtx { int wm, wn, cn, rq; };
__device__ __forceinline__ TileCtx tctx(){
  TileCtx t;
  const int wave = threadIdx.x >> 6, lane = threadIdx.x & 63;
  t.wm = blockIdx.y * 128 + (wave & 1) * 64;
  t.wn = blockIdx.x * 128 + (wave >> 1) * 64;
  t.cn = lane & 15; t.rq = (lane >> 4) * 4;
  return t;
}
#define ACC_ZERO(acc) { _Pragma("unroll") for (int i=0;i<4;++i) _Pragma("unroll") for (int j=0;j<4;++j) _Pragma("unroll") for (int r=0;r<4;++r) acc[i][j][r]=0.f; }

// merged Fq/Gk conv (z=0: content->Fq, z=1: style->Gk), split in/out + bias[n]
__global__ __launch_bounds__(256) void g_conv_split2(const u16* __restrict__ A0h, const u16* __restrict__ A0l,
                                                     const u16* __restrict__ A1h, const u16* __restrict__ A1l,
                                                     const u16* __restrict__ B0h, const u16* __restrict__ B0l,
                                                     const u16* __restrict__ B1h, const u16* __restrict__ B1l,
                                                     const float* __restrict__ bias0, const float* __restrict__ bias1,
                                                     u16* __restrict__ O0h, u16* __restrict__ O0l,
                                                     u16* __restrict__ O1h, u16* __restrict__ O1l){
  __shared__ u16 lds[16384];
  const int z = blockIdx.z;
  const u16* Ah = z ? A1h : A0h;  const u16* Al = z ? A1l : A0l;
  const u16* Bh = z ? B1h : B0h;  const u16* Bl = z ? B1l : B0l;
  const float* bias = z ? bias1 : bias0;
  u16* Ohi = z ? O1h : O0h;  u16* Olo = z ? O1l : O0l;
  TileCtx t = tctx();
  f32x4 acc[4][4]; ACC_ZERO(acc);
  mfma_core<true>(Ah + (size_t)blockIdx.y*128*C, Al + (size_t)blockIdx.y*128*C, C,
                  Bh + (size_t)blockIdx.x*128*C, Bl + (size_t)blockIdx.x*128*C, C, C, lds, acc);
  #pragma unroll
  for (int fm = 0; fm < 4; ++fm)
    #pragma unroll
    for (int fn = 0; fn < 4; ++fn)
      #pragma unroll
      for (int r = 0; r < 4; ++r){
        int gm = t.wm + fm*16 + t.rq + r;
        int gn = t.wn + fn*16 + t.cn;
        float v = acc[fm][fn][r] + bias[gn];
        u16 h = f2bf(v);
        Ohi[(size_t)gm*C + gn] = h;
        Olo[(size_t)gm*C + gn] = f2bf(v - bf2f(h));
      }
}

// split GEMM -> fp32 out (score logits T2)
__global__ __launch_bounds__(256) void g_gemm_split_f32(const u16* __restrict__ Ah, const u16* __restrict__ Al, int pA,
                                                        const u16* __restrict__ Bh, const u16* __restrict__ Bl, int pB,
                                                        int K, float* __restrict__ O, int pO){
  __shared__ u16 lds[16384];
  TileCtx t = tctx();
  f32x4 acc[4][4]; ACC_ZERO(acc);
  mfma_core<true>(Ah + (size_t)blockIdx.y*128*pA, Al + (size_t)blockIdx.y*128*pA, pA,
                  Bh + (size_t)blockIdx.x*128*pB, Bl + (size_t)blockIdx.x*128*pB, pB, K, lds, acc);
  #pragma unroll
  for (int fm = 0; fm < 4; ++fm)
    #pragma unroll
    for (int fn = 0; fn < 4; ++fn)
      #pragma unroll
      for (int r = 0; r < 4; ++r)
        O[(size_t)(t.wm + fm*16 + t.rq + r)*pO + t.wn + fn*16 + t.cn] = acc[fm][fn][r];
}

// plain GEMM + bias[m] -> bf16 out (Hv conv)
__global__ __launch_bounds__(256) void g_gemm_biasm_bf16(const u16* __restrict__ A, int pA,
                                                         const u16* __restrict__ B, int pB,
                                                         int K, const float* __restrict__ bias,
                                                         u16* __restrict__ O, int pO){
  __shared__ u16 lds[8192];
  TileCtx t = tctx();
  f32x4 acc[4][4]; ACC_ZERO(acc);
  mfma_core<false>(A + (size_t)blockIdx.y*128*pA, nullptr, pA,
                   B + (size_t)blockIdx.x*128*pB, nullptr, pB, K, lds, acc);
  #pragma unroll
  for (int fm = 0; fm < 4; ++fm)
    #pragma unroll
    for (int fn = 0; fn < 4; ++fn)
      #pragma unroll
      for (int r = 0; r < 4; ++r){
        int gm = t.wm + fm*16 + t.rq + r;
        O[(size_t)gm*pO + t.wn + fn*16 + t.cn] = f2bf(acc[fm][fn][r] + bias[gm]);
      }
}

// split-K GEMM -> fp32 partials [z][M][N] (ogemm, pgemm)
__global__ __launch_bounds__(256) void g_gemm_partial(const u16* __restrict__ A, int pA,
                                                      const u16* __restrict__ B, int pB,
                                                      int Kper, float* __restrict__ O, int pO,
                                                      size_t sliceStride){
  __shared__ u16 lds[8192];
  TileCtx t = tctx();
  const int koff = blockIdx.z * Kper;
  f32x4 acc[4][4]; ACC_ZERO(acc);
  mfma_core<false>(A + (size_t)blockIdx.y*128*pA + koff, nullptr, pA,
                   B + (size_t)blockIdx.x*128*pB + koff, nullptr, pB, Kper, lds, acc);
  float* Oz = O + (size_t)blockIdx.z * sliceStride;
  #pragma unroll
  for (int fm = 0; fm < 4; ++fm)
    #pragma unroll
    for (int fn = 0; fn < 4; ++fn)
      #pragma unroll
      for (int r = 0; r < 4; ++r)
        Oz[(size_t)(t.wm + fm*16 + t.rq + r)*pO + t.wn + fn*16 + t.cn] = acc[fm][fn][r];
}

// reduce S fp32 partials -> bf16 (4 elems/thread)
__global__ __launch_bounds__(256) void k_reduce(const float* __restrict__ in, size_t sliceStride,
                                                int S, u16* __restrict__ out){
  const size_t i4 = ((size_t)blockIdx.x*256 + threadIdx.x) * 4;
  float4 s = *(const float4*)&in[i4];
  for (int z = 1; z < S; ++z){
    float4 v = *(const float4*)&in[(size_t)z*sliceStride + i4];
    s.x += v.x; s.y += v.y; s.z += v.z; s.w += v.w;
  }
  u16 r0 = f2bf(s.x), r1 = f2bf(s.y), r2 = f2bf(s.z), r3 = f2bf(s.w);
  uint2 uo; uo.x = (unsigned)r0 | ((unsigned)r1 << 16);
  uo.y = (unsigned)r2 | ((unsigned)r3 << 16);
  *(uint2*)&out[i4] = uo;
}

// out-conv: + bias[m] + residual[m][n] (fp32), fp32 out pitch HW
__global__ __launch_bounds__(256) void g_gemm_outconv(const u16* __restrict__ A, int pA,
                                                      const u16* __restrict__ B, int pB,
                                                      int K, const float* __restrict__ bias,
                                                      const float* __restrict__ res,
                                                      float* __restrict__ O){
  __shared__ u16 lds[8192];
  TileCtx t = tctx();
  f32x4 acc[4][4]; ACC_ZERO(acc);
  mfma_core<false>(A + (size_t)blockIdx.y*128*pA, nullptr, pA,
                   B + (size_t)blockIdx.x*128*pB, nullptr, pB, K, lds, acc);
  #pragma unroll
  for (int fm = 0; fm < 4; ++fm)
    #pragma unroll
    for (int fn = 0; fn < 4; ++fn)
      #pragma unroll
      for (int r = 0; r < 4; ++r){
        int gm = t.wm + fm*16 + t.rq + r;
        int gn = t.wn + fn*16 + t.cn;
        O[(size_t)gm*HW + gn] = acc[fm][fn][r] + bias[gm] + res[(size_t)gm*HW + gn];
      }
}

// hmid: lrelu(acc*inc[m] + b1[n]) -> fp32 out pitch HID
__global__ __launch_bounds__(256) void g_gemm_hmid(const u16* __restrict__ A, int pA,
                                                   const u16* __restrict__ B, int pB,
                                                   int K, const float* __restrict__ inc,
                                                   const float* __restrict__ b1,
                                                   float* __restrict__ O){
  __shared__ u16 lds[8192];
  TileCtx t = tctx();
  f32x4 acc[4][4]; ACC_ZERO(acc);
  mfma_core<false>(A + (size_t)blockIdx.y*128*pA, nullptr, pA,
                   B + (size_t)blockIdx.x*128*pB, nullptr, pB, K, lds, acc);
  #pragma unroll
  for (int fm = 0; fm < 4; ++fm)
    #pragma unroll
    for (int fn = 0; fn < 4; ++fn)
      #pragma unroll
      for (int r = 0; r < 4; ++r){
        int gm = t.wm + fm*16 + t.rq + r;
        int gn = t.wn + fn*16 + t.cn;
        float h = acc[fm][fn][r] * inc[gm] + b1[gn];
        O[(size_t)gm*HID + gn] = (h > 0.f) ? h : 0.2f*h;
      }
}

// ---------------- prep kernels ----------------------------------------------
__global__ __launch_bounds__(256) void k_stats(const float* __restrict__ content,
                                               const float* __restrict__ style,
                                               float2* __restrict__ statsC,
                                               float2* __restrict__ statsS){
  const int bc = blockIdx.x;
  const float* X = (blockIdx.y == 0 ? content : style) + (size_t)bc * HW;
  float s = 0.f, sq = 0.f;
  for (int i = threadIdx.x; i < HW; i += 256){ float v = X[i]; s += v; sq += v*v; }
  __shared__ float rs[256], rq[256];
  rs[threadIdx.x] = s; rq[threadIdx.x] = sq; __syncthreads();
  for (int o = 128; o > 0; o >>= 1){
    if (threadIdx.x < o){ rs[threadIdx.x] += rs[threadIdx.x+o]; rq[threadIdx.x] += rq[threadIdx.x+o]; }
    __syncthreads();
  }
  if (threadIdx.x == 0){
    float mean = rs[0] / (float)HW;
    float var  = (rq[0] - rs[0]*mean) / (float)(HW - 1);
    (blockIdx.y == 0 ? statsC : statsS)[bc] = make_float2(mean, rsqrtf(var + 1e-5f));
  }
}

__global__ __launch_bounds__(256) void k_pixnorm(const float* __restrict__ content,
                                                 const float* __restrict__ style,
                                                 float* __restrict__ inc,
                                                 float* __restrict__ ins){
  const int b = blockIdx.y;
  const int k = blockIdx.x * 256 + threadIdx.x;
  const float* X = (blockIdx.z == 0 ? content : style) + (size_t)b * C * HW + k;
  float acc = 0.f;
  for (int c = 0; c < C; ++c){ float v = X[(size_t)c * HW]; acc += v*v; }
  (blockIdx.z == 0 ? inc : ins)[b*HW + k] = 1.f / fmaxf(sqrtf(acc), 1e-12f);
}

// transpose X[C][HW] -> XT[HW][C]: mvn split (hi,lo) + raw bf16. z picks src.
__global__ __launch_bounds__(256) void k_prep2(const float* __restrict__ Xc,
                                               const float* __restrict__ Xs,
                                               const float2* __restrict__ stC,
                                               const float2* __restrict__ stS,
                                               u16* __restrict__ ThiC, u16* __restrict__ TloC, u16* __restrict__ TrawC,
                                               u16* __restrict__ ThiS, u16* __restrict__ TloS, u16* __restrict__ TrawS){
  const int z = blockIdx.z;
  const float* X = z ? Xs : Xc;
  const float2* stats = z ? stS : stC;
  u16* Thi = z ? ThiS : ThiC;  u16* Tlo = z ? TloS : TloC;  u16* Traw = z ? TrawS : TrawC;
  __shared__ float tile[64][65];
  __shared__ float2 st[64];
  const int k0 = blockIdx.x*64, c0 = blockIdx.y*64;
  const int t = threadIdx.x;
  if (t < 64) st[t] = stats[c0 + t];
  const int j4 = (t & 15) * 4, i0 = t >> 4;
  for (int r = 0; r < 4; ++r){
    int i = i0 + r*16;
    float4 v = *(const float4*)&X[(size_t)(c0+i)*HW + k0 + j4];
    tile[i][j4+0] = v.x; tile[i][j4+1] = v.y; tile[i][j4+2] = v.z; tile[i][j4+3] = v.w;
  }
  __syncthreads();
  const int kk = t >> 2, cc = (t & 3) * 16;
  u16 h[16], l[16], rw[16];
  #pragma unroll
  for (int q = 0; q < 16; ++q){
    float x = tile[cc+q][kk];
    float2 s = st[cc+q];
    rw[q] = f2bf(x);
    float v = (x - s.x) * s.y;
    h[q] = f2bf(v);
    l[q] = f2bf(v - bf2f(h[q]));
  }
  size_t o = (size_t)(k0+kk)*C + c0 + cc;
  #pragma unroll
  for (int q = 0; q < 16; ++q){ Thi[o+q] = h[q]; Tlo[o+q] = l[q]; Traw[o+q] = rw[q]; }
}

// styleS[c][l] = bf16(style[c,l]*ins[l])
__global__ __launch_bounds__(256) void k_scaleS(const float* __restrict__ style,
                                                const float* __restrict__ ins,
                                                u16* __restrict__ out){
  const size_t idx = ((size_t)blockIdx.x*256 + threadIdx.x) * 4;
  const int l = (int)(idx % HW);
  float4 v = *(const float4*)&style[idx];
  float4 s = *(const float4*)&ins[l];
  out[idx+0] = f2bf(v.x*s.x); out[idx+1] = f2bf(v.y*s.y);
  out[idx+2] = f2bf(v.z*s.z); out[idx+3] = f2bf(v.w*s.w);
}

// weight prep: split Wf,Wg ; bf16 Wh,Wout,W1
__global__ __launch_bounds__(256) void k_wprep(const float* __restrict__ Wf, const float* __restrict__ Wg,
                                               const float* __restrict__ Wh, const float* __restrict__ Wo,
                                               const float* __restrict__ W1,
                                               u16* __restrict__ Wfh, u16* __restrict__ Wfl,
                                               u16* __restrict__ Wgh, u16* __restrict__ Wgl,
                                               u16* __restrict__ Whb, u16* __restrict__ Wob,
                                               u16* __restrict__ W1b){
  const int idx = (blockIdx.x*256 + threadIdx.x) * 4;
  const int mode = blockIdx.y;
  const int nsmall = C*C;
  if (mode == 4){
    float4 v = *(const float4*)&W1[idx];
    W1b[idx+0]=f2bf(v.x); W1b[idx+1]=f2bf(v.y); W1b[idx+2]=f2bf(v.z); W1b[idx+3]=f2bf(v.w);
    return;
  }
  if (idx >= nsmall) return;
  const float* src = (mode==0)?Wf:(mode==1)?Wg:(mode==2)?Wh:Wo;
  float4 v = *(const float4*)&src[idx];
  float vv[4] = {v.x, v.y, v.z, v.w};
  if (mode <= 1){
    u16* oh = (mode==0)?Wfh:Wgh;  u16* ol = (mode==0)?Wfl:Wgl;
    #pragma unroll
    for (int q = 0; q < 4; ++q){
      u16 hh = f2bf(vv[q]);
      oh[idx+q] = hh; ol[idx+q] = f2bf(vv[q] - bf2f(hh));
    }
  } else {
    u16* ob = (mode==2)?Whb:Wob;
    #pragma unroll
    for (int q = 0; q < 4; ++q) ob[idx+q] = f2bf(vv[q]);
  }
}

// clamp[k] = 0.4 + 0.5*sigmoid(dot(hmid[k,:],W2)+b2)
__global__ __launch_bounds__(256) void k_psi(const float* __restrict__ hmid,
                                             const float* __restrict__ W2,
                                             const float* __restrict__ b2,
                                             float* __restrict__ clampv){
  const int k = blockIdx.x, tid = threadIdx.x;
  __shared__ float red[256];
  red[tid] = hmid[(size_t)k*HID + tid] * W2[tid];
  __syncthreads();
  for (int o = 128; o > 0; o >>= 1){
    if (tid < o) red[tid] += red[tid+o];
    __syncthreads();
  }
  if (tid == 0){
    float psi = 1.f/(1.f + expf(-(red[0] + b2[0])));
    clampv[k] = psi*0.5f + 0.4f;
  }
}

// row softmax of T2[k,:] then sigmoid(50*(S-clamp)) -> bf16 in-place (row head)
__global__ __launch_bounds__(256) void k_softgate(float* __restrict__ T2,
                                                  const float* __restrict__ clampv){
  const int k = blockIdx.x, tid = threadIdx.x;
  float* row = &T2[(size_t)k*HW];
  float vals[16];
  float mx = -3.4e38f;
  #pragma unroll
  for (int i = 0; i < 16; ++i){ vals[i] = row[tid + i*256]; mx = fmaxf(mx, vals[i]); }
  __shared__ float red[256];
  red[tid] = mx; __syncthreads();
  for (int o = 128; o > 0; o >>= 1){
    if (tid < o) red[tid] = fmaxf(red[tid], red[tid+o]);
    __syncthreads();
  }
  mx = red[0]; __syncthreads();
  float s = 0.f;
  #pragma unroll
  for (int i = 0; i < 16; ++i){ vals[i] = expf(vals[i] - mx); s += vals[i]; }
  red[tid] = s; __syncthreads();
  for (int o = 128; o > 0; o >>= 1){
    if (tid < o) red[tid] += red[tid+o];
    __syncthreads();
  }
  const float inv = 1.f / red[0];
  const float cv = clampv[k];
  u16* Sg = (u16*)row;
  #pragma unroll
  for (int i = 0; i < 16; ++i){
    float sg = 1.f/(1.f + expf(-50.f*(vals[i]*inv - cv)));
    Sg[tid + i*256] = f2bf(sg);
  }
}

extern "C" void kernel_launch(void* const* d_in, const int* in_sizes, int n_in,
                              void* d_out, int out_size, void* d_ws, size_t ws_size,
                              hipStream_t stream){
  const float* content = (const float*)d_in[0];
  const float* style   = (const float*)d_in[1];
  const float* Wf   = (const float*)d_in[2];  const float* bfv  = (const float*)d_in[3];
  const float* Wg   = (const float*)d_in[4];  const float* bg   = (const float*)d_in[5];
  const float* Wh   = (const float*)d_in[6];  const float* bh   = (const float*)d_in[7];
  const float* Wo   = (const float*)d_in[8];  const float* bout = (const float*)d_in[9];
  const float* W1   = (const float*)d_in[10]; const float* b1   = (const float*)d_in[11];
  const float* W2   = (const float*)d_in[12]; const float* b2   = (const float*)d_in[13];
  float* out = (float*)d_out;

  char* ws = (char*)d_ws;
  size_t off = 0;
  auto alloc = [&](size_t bytes)->void*{
    void* p = (void*)(ws + off);
    off += (bytes + 255) & ~(size_t)255;
    return p;
  };
  float2* statsC = (float2*)alloc((size_t)Bn*C*sizeof(float2));
  float2* statsS = (float2*)alloc((size_t)Bn*C*sizeof(float2));
  float*  inc    = (float*) alloc((size_t)Bn*HW*sizeof(float));
  float*  ins    = (float*) alloc((size_t)Bn*HW*sizeof(float));
  float*  clampv = (float*) alloc((size_t)Bn*HW*sizeof(float));
  u16* Wfh = (u16*)alloc((size_t)C*C*2), *Wfl = (u16*)alloc((size_t)C*C*2);
  u16* Wgh = (u16*)alloc((size_t)C*C*2), *Wgl = (u16*)alloc((size_t)C*C*2);
  u16* Whb = (u16*)alloc((size_t)C*C*2), *Wob = (u16*)alloc((size_t)C*C*2);
  u16* W1b = (u16*)alloc((size_t)HID*HW*2);
  u16* XcTh = (u16*)alloc((size_t)HW*C*2), *XcTl = (u16*)alloc((size_t)HW*C*2);
  u16* CrT  = (u16*)alloc((size_t)HW*C*2);
  u16* XsTh = (u16*)alloc((size_t)HW*C*2), *XsTl = (u16*)alloc((size_t)HW*C*2);
  u16* SrT  = (u16*)alloc((size_t)HW*C*2);
  u16* stS  = (u16*)alloc((size_t)C*HW*2);
  u16* FqTh = (u16*)alloc((size_t)HW*C*2), *FqTl = (u16*)alloc((size_t)HW*C*2);
  u16* GkTh = (u16*)alloc((size_t)HW*C*2), *GkTl = (u16*)alloc((size_t)HW*C*2);
  u16* Hvb  = (u16*)alloc((size_t)C*HW*2);
  u16* O1T  = (u16*)alloc((size_t)HW*C*2);
  u16* PT   = (u16*)alloc((size_t)HID*C*2);
  float* hmid  = (float*)alloc((size_t)HW*HID*sizeof(float));
  float* Ppart = (float*)alloc((size_t)16*HID*C*sizeof(float));   // 8 MB
  float* Opart = (float*)alloc((size_t)4*HW*C*sizeof(float));     // 32 MB
  float* T2    = (float*)alloc((size_t)HW*HW*sizeof(float));      // 64 MB (Sg in-place)
  (void)ws_size; (void)in_sizes; (void)n_in; (void)out_size;

  k_stats  <<<dim3(Bn*C, 2),       256, 0, stream>>>(content, style, statsC, statsS);
  k_pixnorm<<<dim3(HW/256, Bn, 2), 256, 0, stream>>>(content, style, inc, ins);
  k_wprep  <<<dim3(HID*HW/1024, 5),256, 0, stream>>>(Wf, Wg, Wh, Wo, W1,
                                                     Wfh, Wfl, Wgh, Wgl, Whb, Wob, W1b);

  for (int b = 0; b < Bn; ++b){
    const float* cb = content + (size_t)b*C*HW;
    const float* sb = style   + (size_t)b*C*HW;
    const float* incb = inc + (size_t)b*HW;
    const float* insb = ins + (size_t)b*HW;
    float* clb = clampv + (size_t)b*HW;

    k_prep2 <<<dim3(HW/64, C/64, 2), 256, 0, stream>>>(cb, sb, statsC + (size_t)b*C, statsS + (size_t)b*C,
                                                       XcTh, XcTl, CrT, XsTh, XsTl, SrT);
    k_scaleS<<<dim3(C*HW/1024),   256, 0, stream>>>(sb, insb, stS);

    // FqT/GkT in one launch: z=0 content->Fq (Wf), z=1 style->Gk (Wg)
    g_conv_split2<<<dim3(C/128, HW/128, 2), 256, 0, stream>>>(
        XcTh, XcTl, XsTh, XsTl, Wfh, Wfl, Wgh, Wgl, bfv, bg,
        FqTh, FqTl, GkTh, GkTl);
    // Hv[c][l] = sum_c' Wh[c,c']*style[c',l] + bh
    g_gemm_biasm_bf16<<<dim3(HW/128, C/128), 256, 0, stream>>>(Whb, C, SrT, C, C, bh, Hvb, HW);
    // PT[o][c] = sum_l W1[o,l]*styleS[c,l]  -- split-K 16 x 256
    g_gemm_partial<<<dim3(C/128, HID/128, 16), 256, 0, stream>>>(W1b, HW, stS, HW, 256,
                                                                 Ppart, C, (size_t)HID*C);
    k_reduce<<<dim3(HID*C/1024), 256, 0, stream>>>(Ppart, (size_t)HID*C, 16, PT);
    // hmid[k][o] = lrelu(inc[k]*sum_c CrT[k,c]*PT[o,c] + b1[o])
    g_gemm_hmid<<<dim3(HID/128, HW/128), 256, 0, stream>>>(CrT, C, PT, C, C, incb, b1, hmid);
    k_psi<<<dim3(HW), 256, 0, stream>>>(hmid, W2, b2, clb);
    // T2[k][l] = sum_o FqT[k,o]*GkT[l,o]
    g_gemm_split_f32<<<dim3(HW/128, HW/128), 256, 0, stream>>>(FqTh, FqTl, C, GkTh, GkTl, C, C, T2, HW);
    k_softgate<<<dim3(HW), 256, 0, stream>>>(T2, clb);
    // O1T[k][c] = sum_l Sg[k,l]*Hv[c,l]  -- split-K 4 x 1024 (Sg pitch 2*HW in T2)
    g_gemm_partial<<<dim3(C/128, HW/128, 4), 256, 0, stream>>>((const u16*)T2, 2*HW, Hvb, HW, 1024,
                                                               Opart, C, (size_t)HW*C);
    k_reduce<<<dim3(HW*C/1024), 256, 0, stream>>>(Opart, (size_t)HW*C, 4, O1T);
    // out[o][k] = sum_c Wout[o,c]*O1T[k,c] + bout[o] + content[o,k]
    g_gemm_outconv<<<dim3(HW/128, C/128), 256, 0, stream>>>(Wob, C, O1T, C, C, bout, cb, out + (size_t)b*C*HW);
  }
}